// Round 17
// baseline (1296.447 us; speedup 1.0000x reference)
//
#include <hip/hip_runtime.h>

#define B_ 256
#define S_ 128
#define SP1 (S_+1)
#define F_ 512
#define H_ 1024
#define A_ 18
#define M_ (B_*S_)      // 32768 output rows (b*S+s)
#define G_ (4*H_)       // 4096 gate cols, permuted unit-major: p = unit*4 + {i,f,g,o}
#define CH_ 16          // timesteps per chunk
#define CR_ (B_*CH_)    // 4096 rows per chunk
#define COG_TN 10       // col-tiles (x256) co-scheduled; remainder standalone

typedef unsigned short u16;
typedef __attribute__((ext_vector_type(8))) _Float16 f16x8;  // 8 fp16 = 4 VGPR
typedef __attribute__((ext_vector_type(4))) _Float16 f16x4;
typedef __attribute__((ext_vector_type(8))) short   s16x8;
typedef __attribute__((ext_vector_type(4))) float f32x4;
typedef __attribute__((ext_vector_type(4))) unsigned int u32x4;

__device__ __forceinline__ float bf2f(u16 u){
  union{unsigned int i; float f;} v; v.i=((unsigned int)u)<<16; return v.f;
}
__device__ __forceinline__ u16 f2bf(float f){
  unsigned int i=__float_as_uint(f);
  unsigned int r=(i+0x7fffu+((i>>16)&1u))>>16;   // RNE
  return (u16)r;
}
__device__ __forceinline__ u16 f2h(float f){
  _Float16 h=(_Float16)f;
  union{_Float16 h; u16 u;} v; v.h=h; return v.u;
}
__device__ __forceinline__ float ldf(const void* p, size_t i, int m){
  return m ? ((const float*)p)[i] : bf2f(((const u16*)p)[i]);
}
// load 8 logical floats -> fp16x8. mode 0: bf16 src, 1: fp32 src, 2: raw fp16 src.
__device__ __forceinline__ f16x8 load8_h(const void* base, size_t off, int m){
  f16x8 v;
  if(m==2) return *(const f16x8*)((const u16*)base + off);
  if(m==1){
    const float* f=(const float*)base + off;
    float4 a=*(const float4*)f; float4 b=*(const float4*)(f+4);
    v[0]=(_Float16)a.x; v[1]=(_Float16)a.y; v[2]=(_Float16)a.z; v[3]=(_Float16)a.w;
    v[4]=(_Float16)b.x; v[5]=(_Float16)b.y; v[6]=(_Float16)b.z; v[7]=(_Float16)b.w;
    return v;
  }
  s16x8 w=*(const s16x8*)((const u16*)base + off);
#pragma unroll
  for(int k=0;k<8;k++) v[k]=(_Float16)bf2f((u16)w[k]);
  return v;
}

// ---- coherent (cross-XCD, LLC-routed) accesses: bypass L1+L2 via sc0 sc1.
__device__ __forceinline__ void store_c2(u16* p, u16 v){
  unsigned int vv=v;
  asm volatile("global_store_short %0, %1, off sc0 sc1" :: "v"(p), "v"(vv) : "memory");
}
__device__ __forceinline__ int load_c4(const int* p){
  int r;
  asm volatile("global_load_dword %0, %1, off sc0 sc1" : "=v"(r) : "v"(p));
  return r;
}
__device__ __forceinline__ void store_c4(int* p, int v){
  asm volatile("global_store_dword %0, %1, off sc0 sc1" :: "v"(p), "v"(v) : "memory");
}

// ---- store-flag group barrier (32 blocks)
__device__ __forceinline__ void bar_flags32(int* flags, int target, int gi, int lane, int w){
  asm volatile("s_waitcnt vmcnt(0)" ::: "memory");   // own h stores at LLC
  __syncthreads();
  if(w==0){
    if(lane==0) store_c4(flags+gi, target);
    while(true){
      int v=load_c4(flags+(lane&31));
      asm volatile("s_waitcnt vmcnt(0)" ::: "memory");
      if(__all(v>=target)) break;
      __builtin_amdgcn_s_sleep(1);
    }
  }
  __syncthreads();
}

// ---- Stage ROWS x 64 fp16 tile into LDS [ROWS][64], XOR-swizzled (256-thr blocks).
template<int ROWS, int MAP>
__device__ __forceinline__ void stage(const void* base, int mode, int lda, int k0,
                                      int rowoff, int t0, u16* lds, int tid){
  if(mode==2){
    constexpr int NI=(ROWS*8)/256;
    int wv=tid>>6, l=tid&63;
#pragma unroll
    for(int i=0;i<NI;i++){
      int s0=i*256+(wv<<6), s=s0+l;
      int r=s>>3, gc=(s&7)^(r&7);
      int p=rowoff+r, sr;
      if(MAP==0)      sr=p;
      else if(MAP==1) sr=(p&3)*H_+(p>>2);
      else            sr=(p>>4)*S_+t0+(p&15);
      const u16* src=(const u16*)base + (size_t)sr*lda + k0 + gc*8;
      u16* dst=lds + s0*8;             // wave-uniform; HW adds lane*16B
      __builtin_amdgcn_global_load_lds((const __attribute__((address_space(1))) unsigned int*)src,
                                       (__attribute__((address_space(3))) unsigned int*)dst,
                                       16, 0, 0);
    }
  } else {
#pragma unroll
    for(int s0=tid; s0<ROWS*8; s0+=256){
      int r=s0>>3, gc=s0&7, lc=gc^(r&7);
      int p=rowoff+r, sr;
      if(MAP==0)      sr=p;
      else if(MAP==1) sr=(p&3)*H_+(p>>2);
      else            sr=(p>>4)*S_+t0+(p&15);
      f16x8 v=load8_h(base, (size_t)sr*lda + k0 + gc*8, mode);
      *(f16x8*)(lds + r*64 + lc*8)=v;
    }
  }
}

// MFMA 16x16x32 fragment from swizzled LDS tile [*][64].
__device__ __forceinline__ f16x8 frag_ld(const u16* lds, int r0, int kc, int lane){
  int r = r0 + (lane&15);
  int c = (kc + (lane>>4)) ^ (r&7);
  return *(const f16x8*)(lds + r*64 + c*8);
}

// ---- 128x128-tile GEMM. OUTMODE 0: relu+fp16. 1: fp32. 2: fp16.
template<int AMAP, int BMAP, int OUTMODE>
__global__ __launch_bounds__(256,3) void gemm128(const void* A, const void* Bt, void* C,
    const float* __restrict__ biasf, const int* __restrict__ flag,
    int K, int lda, int ldb, int ldc, int t0, int amode, int bmode){
  int m=*flag;
  int am = amode<0 ? m : amode;
  int bm_ = bmode<0 ? m : bmode;
  __shared__ u16 As[128*64];
  __shared__ u16 Bs[128*64];
  int tid=threadIdx.x, lane=tid&63, w=tid>>6;
  int bm=blockIdx.y*128, bn=blockIdx.x*128;
  int wm=(w&1)*64, wn=(w>>1)*64;
  f32x4 acc[4][4];
#pragma unroll
  for(int i=0;i<4;i++)
#pragma unroll
    for(int j=0;j<4;j++) acc[i][j]=(f32x4)(0.f);
  for(int k0=0;k0<K;k0+=64){
    stage<128,AMAP>(A , am,  lda, k0, bm, t0, As, tid);
    stage<128,BMAP>(Bt, bm_, ldb, k0, bn, t0, Bs, tid);
    __syncthreads();
#pragma unroll
    for(int kk=0;kk<2;kk++){
      f16x8 af[4], bq[4];
#pragma unroll
      for(int i=0;i<4;i++) af[i]=frag_ld(As, wm+i*16, kk*4, lane);
#pragma unroll
      for(int j=0;j<4;j++) bq[j]=frag_ld(Bs, wn+j*16, kk*4, lane);
#pragma unroll
      for(int i=0;i<4;i++)
#pragma unroll
        for(int j=0;j<4;j++)
          acc[i][j]=__builtin_amdgcn_mfma_f32_16x16x32_f16(af[i],bq[j],acc[i][j],0,0,0);
    }
    __syncthreads();
  }
  int rl=lane>>4, cl=lane&15;
#pragma unroll
  for(int j=0;j<4;j++){
    int col=bn+wn+j*16+cl;
    float bb=biasf[col];
#pragma unroll
    for(int i=0;i<4;i++){
#pragma unroll
      for(int r=0;r<4;r++){
        int row=bm+wm+i*16+rl*4+r;
        float v=acc[i][j][r]+bb;
        if(OUTMODE==0){ v=fmaxf(v,0.f); ((u16*)C)[(size_t)row*ldc+col]=f2h(v); }
        else if(OUTMODE==2){ ((u16*)C)[(size_t)row*ldc+col]=f2h(v); }
        else { ((float*)C)[(size_t)row*ldc+col]=v; }
      }
    }
  }
}

// ---- combined persistent chunk-LSTM + LOAD-BALANCED co-scheduled next-chunk xg GEMM.
// Blocks 0-255: LSTM (setprio 1 — latency-critical). Blocks 256..256+COG_TN*32-1:
// gemm tiles (128x256) for next chunk's xg cols [0, COG_TN*256); remainder standalone.
__global__ __launch_bounds__(512,2) void lstm_xg(u16* __restrict__ hh,
        const u16* __restrict__ Whhp, const u16* __restrict__ xgp,
        float* __restrict__ cst, int* __restrict__ cntc, int tbase,
        const u16* __restrict__ xcf, const u16* __restrict__ Wihp,
        const float* __restrict__ biasg, u16* __restrict__ xgn, int t0n){
  __shared__ __align__(16) char lds_raw[16*2048*2];   // 64 KB shared arena
  int tid=threadIdx.x, lane=tid&63, w=tid>>6;

  if(blockIdx.x>=256){
    // ================= xg gemm co-block: 128 rows x 256 cols of next chunk =================
    __builtin_amdgcn_s_setprio(0);
    u16* As2=(u16*)lds_raw;                 // [128][64] 16 KB
    u16* Bs2=(u16*)(lds_raw+16384);         // [256][64] 32 KB
    int gb=blockIdx.x-256;
    int tm=gb&31, tn=gb>>5;                 // tn 0..COG_TN-1
    int bm2=tm*128, bn2=tn*256;
    int wr=w&1, wc=w>>1;
    f32x4 acc[4][4];
#pragma unroll
    for(int i=0;i<4;i++)
#pragma unroll
      for(int j=0;j<4;j++) acc[i][j]=(f32x4)(0.f);
    for(int kt=0;kt<16;kt++){
      int k0=kt*64;
#pragma unroll
      for(int i=0;i<2;i++){
        int s0=w*128+i*64, s=s0+lane;
        int r=s>>3, gc=(s&7)^(r&7);
        int p=bm2+r;
        const u16* src=xcf + ((size_t)(p>>4)*S_ + t0n + (p&15))*H_ + k0 + gc*8;
        __builtin_amdgcn_global_load_lds((const __attribute__((address_space(1))) unsigned int*)src,
                                         (__attribute__((address_space(3))) unsigned int*)(As2+s0*8),
                                         16, 0, 0);
      }
#pragma unroll
      for(int i=0;i<4;i++){
        int s0=w*256+i*64, s=s0+lane;
        int r=s>>3, gc=(s&7)^(r&7);
        const u16* src=Wihp + (size_t)(bn2+r)*H_ + k0 + gc*8;
        __builtin_amdgcn_global_load_lds((const __attribute__((address_space(1))) unsigned int*)src,
                                         (__attribute__((address_space(3))) unsigned int*)(Bs2+s0*8),
                                         16, 0, 0);
      }
      __syncthreads();
#pragma unroll
      for(int kk=0;kk<2;kk++){
        f16x8 af[4], bq[4];
#pragma unroll
        for(int i=0;i<4;i++) af[i]=frag_ld(As2, wr*64+i*16, kk*4, lane);
#pragma unroll
        for(int j=0;j<4;j++) bq[j]=frag_ld(Bs2, wc*64+j*16, kk*4, lane);
#pragma unroll
        for(int i=0;i<4;i++)
#pragma unroll
          for(int j=0;j<4;j++)
            acc[i][j]=__builtin_amdgcn_mfma_f32_16x16x32_f16(af[i],bq[j],acc[i][j],0,0,0);
      }
      __syncthreads();
    }
    int rl=lane>>4, cl=lane&15;
#pragma unroll
    for(int j=0;j<4;j++){
      int col=bn2+wc*64+j*16+cl;
      float bb=biasg[col];
#pragma unroll
      for(int i=0;i<4;i++){
#pragma unroll
        for(int r=0;r<4;r++){
          int row=bm2+wr*64+i*16+rl*4+r;
          ((u16*)xgn)[(size_t)row*G_+col]=f2h(acc[i][j][r]+bb);
        }
      }
    }
    return;
  }
  // ================= LSTM block (gs overlays As; setprio 1) =================
  u16* As=(u16*)lds_raw;                    // 16 k-tiles [32][64] = 64 KB
  float* gs=(float*)lds_raw;                // overlay: used only after MFMA sync
  int grp=blockIdx.x&7, ci=blockIdx.x>>3;
  int bm=grp*32, bn=ci*128;
  int* flags = cntc + grp*64;

  f16x8 bw[32];
#pragma unroll
  for(int t=0;t<32;t++){
    int p = bn + w*16 + (lane&15);
    int k = t*32 + (lane>>4)*8;
    bw[t]=*(const f16x8*)(Whhp + (size_t)p*H_ + k);
  }
#pragma unroll
  for(int t=0;t<32;t++) asm volatile("" : "+a"(bw[t]));
  __builtin_amdgcn_s_setprio(1);            // latency-critical wave: win issue arbitration

  int rl0=tid>>5, rl1=(tid+512)>>5, u0=tid&31;
  int gu=(bn>>2)+u0;
  float c0=cst[(size_t)(bm+rl0)*H_+gu];
  float c1=cst[(size_t)(bm+rl1)*H_+gu];

  for(int dt=0;dt<CH_;dt++){
    f16x4 xv0=*(const f16x4*)(xgp + ((size_t)(bm+rl0)*CH_+dt)*G_ + bn + u0*4);
    f16x4 xv1=*(const f16x4*)(xgp + ((size_t)(bm+rl1)*CH_+dt)*G_ + bn + u0*4);
    if(dt) bar_flags32(flags, tbase+dt, ci, lane, w);
    const u16* hbase = hh + (size_t)(tbase+dt)*H_;   // read slot tbase+dt
    {
      u32x4 tmp[8];
#pragma unroll
      for(int i=0;i<8;i++){
        int s=tid+i*512, kt=s>>8, r=(s>>3)&31, gc=s&7;
        tmp[i]=*(const u32x4*)(hbase + (size_t)(bm+r)*(SP1*H_) + kt*64 + gc*8);
      }
#pragma unroll
      for(int i=0;i<8;i++){
        int s=tid+i*512, kt=s>>8, r=(s>>3)&31, gc=s&7, lc=gc^(r&7);
        *(u32x4*)(As + kt*2048 + r*64 + lc*8)=tmp[i];
      }
    }
    __syncthreads();
    f32x4 acc0=(f32x4)(0.f), acc1=(f32x4)(0.f);
#pragma unroll
    for(int t=0;t<32;t++){
      int kt=t>>1, kk=t&1;
      f16x8 af0=frag_ld(As+kt*2048, 0,  kk*4, lane);
      f16x8 af1=frag_ld(As+kt*2048, 16, kk*4, lane);
      acc0=__builtin_amdgcn_mfma_f32_16x16x32_f16(af0,bw[t],acc0,0,0,0);
      acc1=__builtin_amdgcn_mfma_f32_16x16x32_f16(af1,bw[t],acc1,0,0,0);
    }
    __syncthreads();   // all MFMA reads of As complete before gs overlays it
#pragma unroll
    for(int r=0;r<4;r++){
      gs[(   (lane>>4)*4+r)*132 + w*16+(lane&15)]=acc0[r];
      gs[(16+(lane>>4)*4+r)*132 + w*16+(lane&15)]=acc1[r];
    }
    __syncthreads();
    {
      float4 gv=*(const float4*)&gs[rl0*132+u0*4];
      float ii=1.f/(1.f+__expf(-(gv.x+(float)xv0[0])));
      float ff=1.f/(1.f+__expf(-(gv.y+(float)xv0[1])));
      float gg=1.f-2.f/(__expf(2.f*(gv.z+(float)xv0[2]))+1.f);
      float oo=1.f/(1.f+__expf(-(gv.w+(float)xv0[3])));
      c0=ff*c0+ii*gg;
      float th=1.f-2.f/(__expf(2.f*c0)+1.f);
      store_c2(hh + ((size_t)(bm+rl0)*SP1 + tbase+dt+1)*H_ + gu, f2h(oo*th));
    }
    {
      float4 gv=*(const float4*)&gs[rl1*132+u0*4];
      float ii=1.f/(1.f+__expf(-(gv.x+(float)xv1[0])));
      float ff=1.f/(1.f+__expf(-(gv.y+(float)xv1[1])));
      float gg=1.f-2.f/(__expf(2.f*(gv.z+(float)xv1[2]))+1.f);
      float oo=1.f/(1.f+__expf(-(gv.w+(float)xv1[3])));
      c1=ff*c1+ii*gg;
      float th=1.f-2.f/(__expf(2.f*c1)+1.f);
      store_c2(hh + ((size_t)(bm+rl1)*SP1 + tbase+dt+1)*H_ + gu, f2h(oo*th));
    }
  }
  cst[(size_t)(bm+rl0)*H_+gu]=c0;
  cst[(size_t)(bm+rl1)*H_+gu]=c1;
}

// ---- fallback per-step LSTM (low-ws tier)
__global__ __launch_bounds__(256,2) void lstm_step(u16* __restrict__ hh, int slotAbs, int dt,
        const void* __restrict__ Whh, const u16* __restrict__ xg,
        float* __restrict__ cst, const int* __restrict__ flag){
  int m=*flag;
  __shared__ u16 As[64*64];
  __shared__ u16 Bs[64*64];
  __shared__ float gs[64*64];
  int tid=threadIdx.x, lane=tid&63, w=tid>>6;
  int bm=blockIdx.y*64, bn=blockIdx.x*64;
  int wm=(w&1)*32, wn=(w>>1)*32;
  f32x4 acc[2][2];
#pragma unroll
  for(int i=0;i<2;i++)
#pragma unroll
    for(int j=0;j<2;j++) acc[i][j]=(f32x4)(0.f);
  for(int k0=0;k0<H_;k0+=64){
    stage<64,0>(hh + (size_t)slotAbs*H_, 2, SP1*H_, k0, bm, 0, As, tid);
    stage<64,1>(Whh,                     m, H_,     k0, bn, 0, Bs, tid);
    __syncthreads();
#pragma unroll
    for(int kk=0;kk<2;kk++){
      f16x8 af[2], bq[2];
#pragma unroll
      for(int i=0;i<2;i++) af[i]=frag_ld(As, wm+i*16, kk*4, lane);
#pragma unroll
      for(int j=0;j<2;j++) bq[j]=frag_ld(Bs, wn+j*16, kk*4, lane);
#pragma unroll
      for(int i=0;i<2;i++)
#pragma unroll
        for(int j=0;j<2;j++)
          acc[i][j]=__builtin_amdgcn_mfma_f32_16x16x32_f16(af[i],bq[j],acc[i][j],0,0,0);
    }
    __syncthreads();
  }
  int rl=lane>>4, cl=lane&15;
#pragma unroll
  for(int j=0;j<2;j++){
    int coll=wn+j*16+cl;
#pragma unroll
    for(int i=0;i<2;i++){
#pragma unroll
      for(int r=0;r<4;r++){
        int rowl=wm+i*16+rl*4+r;
        float xv=(float)((const _Float16*)xg)[((size_t)(bm+rowl)*CH_+dt)*G_ + bn+coll];
        gs[rowl*64+coll]=acc[i][j][r] + xv;
      }
    }
  }
  __syncthreads();
#pragma unroll
  for(int p=0;p<4;p++){
    int idx=p*256+tid;
    int rowl=idx>>4, u=idx&15;
    float4 gv = *(const float4*)&gs[rowl*64+u*4];
    float ii=1.f/(1.f+__expf(-gv.x));
    float ff=1.f/(1.f+__expf(-gv.y));
    float gg=1.f-2.f/(__expf(2.f*gv.z)+1.f);
    float oo=1.f/(1.f+__expf(-gv.w));
    int gb=bm+rowl;
    int gu=(bn>>2)+u;
    size_t ci=(size_t)gb*H_+gu;
    float cn=ff*cst[ci]+ii*gg;
    cst[ci]=cn;
    float th=1.f-2.f/(__expf(2.f*cn)+1.f);
    hh[((size_t)gb*SP1 + slotAbs+1)*H_ + gu]=f2h(oo*th);
  }
}

// ---- heads as MFMA GEMM + fused log-softmax (r15-verified).
__global__ __launch_bounds__(512,1) void heads_gemm(const u16* __restrict__ hh,
      const u16* __restrict__ WH, const float* __restrict__ blf,
      const int* __restrict__ acts, void* __restrict__ out, const int* __restrict__ flag){
  int m=*flag;
  __shared__ u16 Bs[16*2048];
  __shared__ u16 As[128*64];
  __shared__ float gs[128*36];
  int tid=threadIdx.x, lane=tid&63, w=tid>>6;
  int bm=blockIdx.x*128;
#pragma unroll
  for(int i=0;i<8;i++){
    int s=tid+i*512;
    int kt=s>>8, r=(s>>3)&31, gc=s&7, lc=gc^(r&7);
    *(f16x8*)(Bs+kt*2048+r*64+lc*8) = *(const f16x8*)(WH + (size_t)r*H_ + kt*64 + gc*8);
  }
  f32x4 acc0=(f32x4)(0.f), acc1=(f32x4)(0.f);
  for(int kt=0;kt<16;kt++){
#pragma unroll
    for(int i=0;i<2;i++){
      int s0=i*512+(w<<6), s=s0+lane;
      int r=s>>3, gc=(s&7)^(r&7);
      int rg=bm+r;
      const u16* src=hh + ((size_t)(rg>>7)*SP1 + (rg&127)+1)*H_ + kt*64 + gc*8;
      u16* dst=As + s0*8;
      __builtin_amdgcn_global_load_lds((const __attribute__((address_space(1))) unsigned int*)src,
                                       (__attribute__((address_space(3))) unsigned int*)dst,
                                       16, 0, 0);
    }
    __syncthreads();
#pragma unroll
    for(int kk=0;kk<2;kk++){
      f16x8 af=frag_ld(As, w*16, kk*4, lane);
      f16x8 b0=frag_ld(Bs+kt*2048, 0,  kk*4, lane);
      f16x8 b1=frag_ld(Bs+kt*2048, 16, kk*4, lane);
      acc0=__builtin_amdgcn_mfma_f32_16x16x32_f16(af,b0,acc0,0,0,0);
      acc1=__builtin_amdgcn_mfma_f32_16x16x32_f16(af,b1,acc1,0,0,0);
    }
    __syncthreads();
  }
#pragma unroll
  for(int r=0;r<4;r++){
    gs[(w*16+(lane>>4)*4+r)*36 + (lane&15)]      = acc0[r];
    gs[(w*16+(lane>>4)*4+r)*36 + 16 + (lane&15)] = acc1[r];
  }
  __syncthreads();
  if(tid<128){
    int rg=bm+tid;
    float lg[18];
#pragma unroll
    for(int j=0;j<18;j++) lg[j]=gs[tid*36+j]+blf[j];
    float value=gs[tid*36+18]+blf[18];
    float mx=lg[0];
#pragma unroll
    for(int j=1;j<18;j++) mx=fmaxf(mx,lg[j]);
    float se=0.f, s1=0.f;
#pragma unroll
    for(int j=0;j<18;j++){ float e=__expf(lg[j]-mx); se+=e; s1+=e*(lg[j]-mx); }
    float lse=__logf(se);
    int a=acts[rg];
    float la=0.f;
#pragma unroll
    for(int j=0;j<18;j++) la = (j==a) ? lg[j] : la;
    float lp=la-mx-lse;
    float ent=lse - s1/se;
    if(m){
      ((float*)out)[rg]=lp; ((float*)out)[M_+rg]=ent; ((float*)out)[2*M_+rg]=value;
    } else {
      ((u16*)out)[rg]=f2bf(lp); ((u16*)out)[M_+rg]=f2bf(ent); ((u16*)out)[2*M_+rg]=f2bf(value);
    }
  }
}

// ---- fallback heads (no-WH tier)
__global__ __launch_bounds__(256,2) void heads_full(const u16* __restrict__ hh,
      const void* __restrict__ Wl, const void* __restrict__ Wv,
      const float* __restrict__ blf, const int* __restrict__ acts,
      void* __restrict__ out, const int* __restrict__ flag){
  int m=*flag;
  int rg = blockIdx.x*4 + (threadIdx.x>>6);
  int lane = threadIdx.x & 63;
  int b=rg>>7, t=rg&(S_-1);
  const u16* h = hh + ((size_t)b*SP1 + t+1)*H_;
  f16x8 h0=*(const f16x8*)(h + lane*16), h1=*(const f16x8*)(h + lane*16 + 8);
  float hv[16];
#pragma unroll
  for(int k=0;k<8;k++){ hv[k]=(float)h0[k]; hv[8+k]=(float)h1[k]; }
  float dots[19];
#pragma unroll
  for(int j=0;j<19;j++){
    const void* wrow = (j<18) ? Wl : Wv;
    size_t roff = (j<18) ? (size_t)j*H_ : 0;
    float wv_[16];
    if(m){
      const float* f=(const float*)wrow + roff + lane*16;
      float4 a=*(const float4*)f, b2=*(const float4*)(f+4), c=*(const float4*)(f+8), d=*(const float4*)(f+12);
      wv_[0]=a.x;wv_[1]=a.y;wv_[2]=a.z;wv_[3]=a.w; wv_[4]=b2.x;wv_[5]=b2.y;wv_[6]=b2.z;wv_[7]=b2.w;
      wv_[8]=c.x;wv_[9]=c.y;wv_[10]=c.z;wv_[11]=c.w; wv_[12]=d.x;wv_[13]=d.y;wv_[14]=d.z;wv_[15]=d.w;
    } else {
      const u16* ub=(const u16*)wrow + roff + lane*16;
      s16x8 w0=*(const s16x8*)ub, w1=*(const s16x8*)(ub+8);
#pragma unroll
      for(int k=0;k<8;k++){ wv_[k]=bf2f((u16)w0[k]); wv_[8+k]=bf2f((u16)w1[k]); }
    }
    float d=0.f;
#pragma unroll
    for(int k=0;k<16;k++) d += hv[k]*wv_[k];
#pragma unroll
    for(int mm=1;mm<64;mm<<=1) d += __shfl_xor(d, mm, 64);
    dots[j]=d;
  }
  float lg[18];
#pragma unroll
  for(int j=0;j<18;j++) lg[j]=dots[j]+blf[j];
  float value=dots[18]+blf[18];
  float mx=lg[0];
#pragma unroll
  for(int j=1;j<18;j++) mx=fmaxf(mx,lg[j]);
  float se=0.f, s1=0.f;
#pragma unroll
  for(int j=0;j<18;j++){ float e=__expf(lg[j]-mx); se+=e; s1+=e*(lg[j]-mx); }
  float lse=__logf(se);
  int a=acts[rg];
  float la=0.f;
#pragma unroll
  for(int j=0;j<18;j++) la = (j==a) ? lg[j] : la;
  float lp=la-mx-lse;
  float ent=lse - s1/se;
  if(lane==0){
    if(m){
      ((float*)out)[rg]=lp; ((float*)out)[M_+rg]=ent; ((float*)out)[2*M_+rg]=value;
    } else {
      ((u16*)out)[rg]=f2bf(lp); ((u16*)out)[M_+rg]=f2bf(ent); ((u16*)out)[2*M_+rg]=f2bf(value);
    }
  }
}

// ---- dtype detect
__global__ void detect(const u16* __restrict__ obs_w, int* __restrict__ flag){
  __shared__ float red[256];
  float mx=0.f;
  for(int i=threadIdx.x;i<4096;i+=256) mx=fmaxf(mx,fabsf(bf2f(obs_w[i])));
  red[threadIdx.x]=mx; __syncthreads();
  for(int s=128;s>0;s>>=1){
    if(threadIdx.x<s) red[threadIdx.x]=fmaxf(red[threadIdx.x],red[threadIdx.x+s]);
    __syncthreads();
  }
  if(threadIdx.x==0) *flag=(red[0]>1e4f)?1:0;
}

// ---- prep
__global__ void prep(const void* bih, const void* bhh, const void* b1, const void* bl, const void* bv,
                     const void* cx, const void* hx,
                     float* biasg, float* b1f, float* blf, float* cst, u16* hh,
                     int* cnt, const int* __restrict__ flag){
  int m=*flag;
  size_t i=(size_t)blockIdx.x*256+threadIdx.x;
  if(i<G_){ size_t rm=(i&3)*H_+(i>>2); biasg[i]=ldf(bih,rm,m)+ldf(bhh,rm,m); return; }
  i-=G_;
  if(i<H_){ b1f[i]=ldf(b1,i,m); return; }
  i-=H_;
  if(i<19){ blf[i]=(i<18)?ldf(bl,i,m):ldf(bv,0,m); return; }
  i-=19;
  if(i<512){ cnt[i]=0; return; }
  i-=512;
  if(i<(size_t)B_*H_){ cst[i]=ldf(cx,i,m); return; }
  i-=(size_t)B_*H_;
  if(i<(size_t)B_*H_){
    size_t b=i>>10, k=i&1023;
    hh[b*(SP1*H_) + k]=f2h(ldf(hx,i,m));   // seed at slot 0
  }
}

// ---- weight pre-conversion
__global__ void convw(const void* W1, const void* Wih, const void* Whh,
                      const void* Wl, const void* Wv,
                      u16* W1h, u16* Wihp, u16* Whhp, u16* WH,
                      const int* __restrict__ flag){
  int m=*flag;
  size_t i=((size_t)blockIdx.x*256+threadIdx.x)*8;
  const size_t n1=(size_t)H_*F_, n2=(size_t)G_*H_, n3=(size_t)32*H_;
  if(i<n1){ *(f16x8*)(W1h+i)=load8_h(W1,i,m); return; }
  i-=n1;
  if(i<n2){ size_t p=i>>10, c=i&1023; size_t sr=(p&3)*H_+(p>>2);
            *(f16x8*)(Wihp+i)=load8_h(Wih, sr*H_+c, m); return; }
  i-=n2;
  if(i<n2){ size_t p=i>>10, c=i&1023; size_t sr=(p&3)*H_+(p>>2);
            *(f16x8*)(Whhp+i)=load8_h(Whh, sr*H_+c, m); return; }
  i-=n2;
  if(i<n3){
    size_t j=i>>10, c=i&1023;
    f16x8 v;
    if(j<18)      v=load8_h(Wl, j*H_+c, m);
    else if(j==18) v=load8_h(Wv, c, m);
    else{ for(int k=0;k<8;k++) v[k]=(_Float16)0.f; }
    *(f16x8*)(WH+i)=v;
  }
}
__global__ void convobs(const void* obs, u16* obsh, const int* __restrict__ flag){
  int m=*flag;
  size_t i=((size_t)blockIdx.x*256+threadIdx.x)*8;
  if(i<(size_t)M_*F_) *(f16x8*)(obsh+i)=load8_h(obs,i,m);
}

extern "C" void kernel_launch(void* const* d_in, const int* in_sizes, int n_in,
                              void* d_out, int out_size, void* d_ws, size_t ws_size,
                              hipStream_t stream){
  const void* obs=d_in[0];
  const void* hx =d_in[1];
  const void* cx =d_in[2];
  const int* acts=(const int*)d_in[3];
  const void* W1 =d_in[4];
  const void* b1 =d_in[5];
  const void* Wih=d_in[6];
  const void* bih=d_in[7];
  const void* Whh=d_in[8];
  const void* bhh=d_in[9];
  const void* Wv =d_in[10];
  const void* bv =d_in[11];
  const void* Wl =d_in[12];
  const void* bl =d_in[13];

  char* w=(char*)d_ws;
  auto alloc=[&](size_t n){ char* p=w; w+=((n+255)&~(size_t)255); return p; };
  int*   flag =(int*)alloc(4);
  int*   cnt  =(int*)alloc(512*4);
  float* biasg=(float*)alloc((size_t)G_*4);
  float* b1f  =(float*)alloc((size_t)H_*4);
  float* blf  =(float*)alloc(32*4);
  float* cst  =(float*)alloc((size_t)B_*H_*4);
  u16*   hh   =(u16*)alloc((size_t)B_*SP1*H_*2);   // 67.6 MB
  u16*   xc   =(u16*)alloc((size_t)CR_*H_*2);      // 8 MB
  u16*   xg   =(u16*)alloc((size_t)CR_*G_*2);      // 32 MB xg A
  // tiers
  size_t nW=((size_t)H_*F_ + 2*(size_t)G_*H_ + 32*(size_t)H_)*2 + 1024;
  bool pathW = ((size_t)(w-(char*)d_ws) + nW) <= ws_size;
  u16 *W1h=0,*Wihp=0,*Whhp=0,*WH=0;
  if(pathW){ W1h=(u16*)alloc((size_t)H_*F_*2); Wihp=(u16*)alloc((size_t)G_*H_*2);
             Whhp=(u16*)alloc((size_t)G_*H_*2); WH=(u16*)alloc((size_t)32*H_*2); }
  size_t nXC=(size_t)M_*H_*2 + 256;
  bool pathXC = pathW && (((size_t)(w-(char*)d_ws) + nXC) <= ws_size);
  u16* xcf=0; if(pathXC) xcf=(u16*)alloc((size_t)M_*H_*2);
  size_t nF=(size_t)CR_*G_*2 + 256;
  bool pathF = pathXC && (((size_t)(w-(char*)d_ws) + nF) <= ws_size);
  u16* xgB=0; if(pathF) xgB=(u16*)alloc((size_t)CR_*G_*2);   // xg B (ping-pong)
  size_t nO=(size_t)M_*F_*2 + 256;
  bool pathO = pathXC && (((size_t)(w-(char*)d_ws) + nO) <= ws_size);
  u16* obsh=0; if(pathO) obsh=(u16*)alloc((size_t)M_*F_*2);

  detect<<<1,256,0,stream>>>((const u16*)obs, flag);
  {
    int total=G_+H_+19+512+B_*H_+B_*H_;
    prep<<<(total+255)/256,256,0,stream>>>(bih,bhh,b1,bl,bv,cx,hx, biasg,b1f,blf,cst,hh,cnt, flag);
  }
  if(pathW){
    size_t n=((size_t)H_*F_+2*(size_t)G_*H_+32*(size_t)H_)/8;
    convw<<<(int)((n+255)/256),256,0,stream>>>(W1,Wih,Whh,Wl,Wv, W1h,Wihp,Whhp,WH, flag);
  }
  if(pathO){
    size_t n=(size_t)M_*F_/8;
    convobs<<<(int)((n+255)/256),256,0,stream>>>(obs, obsh, flag);
  }
  if(pathXC){
    gemm128<0,0,0><<<dim3(H_/128, M_/128),256,0,stream>>>(
        pathO?(const void*)obsh:obs, pathW?(const void*)W1h:W1, xcf, b1f, flag,
        F_, F_, F_, H_, 0, pathO?2:-1, pathW?2:-1);
  }

  const int NC=S_/CH_;
  for(int c=0;c<NC;c++){
    int t0=c*CH_;
    u16* xgcur = (pathF && (c&1)) ? xgB : xg;
    u16* xgnxt = (pathF && !(c&1)) ? xgB : xg;
    if(!pathXC){
      gemm128<2,0,0><<<dim3(H_/128, CR_/128),256,0,stream>>>(
          obs, pathW?(const void*)W1h:W1, xc, b1f, flag, F_, F_, F_, H_, t0, -1, pathW?2:-1);
    }
    // full standalone xg gemm: all chunks unless co-scheduled (then only chunk 0)
    if(!pathF || c==0){
      if(pathXC)
        gemm128<2,0,2><<<dim3(G_/128, CR_/128),256,0,stream>>>(
            xcf, Wihp, xgcur, biasg, flag, H_, H_, H_, G_, t0, 2, 2);
      else if(pathW)
        gemm128<0,0,2><<<dim3(G_/128, CR_/128),256,0,stream>>>(
            xc, Wihp, xgcur, biasg, flag, H_, H_, H_, G_, 0, 2, 2);
      else
        gemm128<0,1,2><<<dim3(G_/128, CR_/128),256,0,stream>>>(
            xc, Wih, xg, biasg, flag, H_, H_, H_, G_, 0, 2, -1);
    }

    if(pathW){
      bool cog = pathF && (c<NC-1);
      int grid = 256 + (cog ? COG_TN*32 : 0);
      lstm_xg<<<grid,512,0,stream>>>(hh, Whhp, xgcur, cst, cnt, t0,
          xcf, Wihp, biasg, cog?xgnxt:(u16*)nullptr, t0+CH_);
      if(cog){
        // remainder cols [COG_TN*256, 4096) of next chunk's xg, standalone
        const int c0=COG_TN*256;
        gemm128<2,0,2><<<dim3((G_-c0)/128, CR_/128),256,0,stream>>>(
            xcf, Wihp+(size_t)c0*H_, xgnxt+c0, biasg+c0, flag,
            H_, H_, H_, G_, t0+CH_, 2, 2);
      }
    } else {
      for(int dt=0;dt<CH_;dt++)
        lstm_step<<<dim3(G_/64, B_/64),256,0,stream>>>(hh, t0+dt, dt, Whh, xg, cst, flag);
    }
  }

  if(pathW)
    heads_gemm<<<dim3(M_/128),512,0,stream>>>(hh, WH, blf, acts, d_out, flag);
  else
    heads_full<<<dim3(M_/4),256,0,stream>>>(hh, Wl, Wv, blf, acts, d_out, flag);
}

// Round 18
// 1033.014 us; speedup vs baseline: 1.2550x; 1.2550x over previous
//
#include <hip/hip_runtime.h>

#define B_ 256
#define S_ 128
#define SP1 (S_+1)
#define F_ 512
#define H_ 1024
#define A_ 18
#define M_ (B_*S_)      // 32768 output rows (b*S+s)
#define G_ (4*H_)       // 4096 gate cols, permuted unit-major: p = unit*4 + {i,f,g,o}
#define CH_ 32          // timesteps per chunk (4 chunks)
#define CR_ (B_*CH_)    // 8192 rows per chunk

typedef unsigned short u16;
typedef __attribute__((ext_vector_type(8))) _Float16 f16x8;  // 8 fp16 = 4 VGPR
typedef __attribute__((ext_vector_type(4))) _Float16 f16x4;
typedef __attribute__((ext_vector_type(8))) short   s16x8;
typedef __attribute__((ext_vector_type(4))) float f32x4;
typedef __attribute__((ext_vector_type(4))) unsigned int u32x4;

__device__ __forceinline__ float bf2f(u16 u){
  union{unsigned int i; float f;} v; v.i=((unsigned int)u)<<16; return v.f;
}
__device__ __forceinline__ u16 f2bf(float f){
  unsigned int i=__float_as_uint(f);
  unsigned int r=(i+0x7fffu+((i>>16)&1u))>>16;   // RNE
  return (u16)r;
}
__device__ __forceinline__ u16 f2h(float f){
  _Float16 h=(_Float16)f;
  union{_Float16 h; u16 u;} v; v.h=h; return v.u;
}
__device__ __forceinline__ float ldf(const void* p, size_t i, int m){
  return m ? ((const float*)p)[i] : bf2f(((const u16*)p)[i]);
}
// load 8 logical floats -> fp16x8. mode 0: bf16 src, 1: fp32 src, 2: raw fp16 src.
__device__ __forceinline__ f16x8 load8_h(const void* base, size_t off, int m){
  f16x8 v;
  if(m==2) return *(const f16x8*)((const u16*)base + off);
  if(m==1){
    const float* f=(const float*)base + off;
    float4 a=*(const float4*)f; float4 b=*(const float4*)(f+4);
    v[0]=(_Float16)a.x; v[1]=(_Float16)a.y; v[2]=(_Float16)a.z; v[3]=(_Float16)a.w;
    v[4]=(_Float16)b.x; v[5]=(_Float16)b.y; v[6]=(_Float16)b.z; v[7]=(_Float16)b.w;
    return v;
  }
  s16x8 w=*(const s16x8*)((const u16*)base + off);
#pragma unroll
  for(int k=0;k<8;k++) v[k]=(_Float16)bf2f((u16)w[k]);
  return v;
}

// ---- coherent (cross-XCD, LLC-routed) accesses: bypass L1+L2 via sc0 sc1.
__device__ __forceinline__ u32x4 load_c16(const void* p){
  u32x4 r;
  asm volatile("global_load_dwordx4 %0, %1, off sc0 sc1" : "=v"(r) : "v"(p));
  return r;
}
__device__ __forceinline__ void store_c2(u16* p, u16 v){
  unsigned int vv=v;
  asm volatile("global_store_short %0, %1, off sc0 sc1" :: "v"(p), "v"(vv) : "memory");
}
__device__ __forceinline__ int load_c4(const int* p){
  int r;
  asm volatile("global_load_dword %0, %1, off sc0 sc1" : "=v"(r) : "v"(p));
  return r;
}
__device__ __forceinline__ void store_c4(int* p, int v){
  asm volatile("global_store_dword %0, %1, off sc0 sc1" :: "v"(p), "v"(v) : "memory");
}

// ---- store-flag group barrier (32 blocks)
__device__ __forceinline__ void bar_flags32(int* flags, int target, int gi, int lane, int w){
  asm volatile("s_waitcnt vmcnt(0)" ::: "memory");   // own h stores at LLC
  __syncthreads();
  if(w==0){
    if(lane==0) store_c4(flags+gi, target);
    while(true){
      int v=load_c4(flags+(lane&31));
      asm volatile("s_waitcnt vmcnt(0)" ::: "memory");
      if(__all(v>=target)) break;
      __builtin_amdgcn_s_sleep(1);
    }
  }
  __syncthreads();
}

// ---- Stage ROWS x 64 fp16 tile into LDS [ROWS][64], XOR-swizzled (256-thr blocks).
// MAP 0: row=rowoff+r. MAP 1: gate-permute. MAP 2: x rows for chunk (rg=b*CH_+dt).
template<int ROWS, int MAP>
__device__ __forceinline__ void stage(const void* base, int mode, int lda, int k0,
                                      int rowoff, int t0, u16* lds, int tid){
  if(mode==2){
    constexpr int NI=(ROWS*8)/256;
    int wv=tid>>6, l=tid&63;
#pragma unroll
    for(int i=0;i<NI;i++){
      int s0=i*256+(wv<<6), s=s0+l;
      int r=s>>3, gc=(s&7)^(r&7);
      int p=rowoff+r, sr;
      if(MAP==0)      sr=p;
      else if(MAP==1) sr=(p&3)*H_+(p>>2);
      else            sr=(p/CH_)*S_+t0+(p%CH_);
      const u16* src=(const u16*)base + (size_t)sr*lda + k0 + gc*8;
      u16* dst=lds + s0*8;             // wave-uniform; HW adds lane*16B
      __builtin_amdgcn_global_load_lds((const __attribute__((address_space(1))) unsigned int*)src,
                                       (__attribute__((address_space(3))) unsigned int*)dst,
                                       16, 0, 0);
    }
  } else {
#pragma unroll
    for(int s0=tid; s0<ROWS*8; s0+=256){
      int r=s0>>3, gc=s0&7, lc=gc^(r&7);
      int p=rowoff+r, sr;
      if(MAP==0)      sr=p;
      else if(MAP==1) sr=(p&3)*H_+(p>>2);
      else            sr=(p/CH_)*S_+t0+(p%CH_);
      f16x8 v=load8_h(base, (size_t)sr*lda + k0 + gc*8, mode);
      *(f16x8*)(lds + r*64 + lc*8)=v;
    }
  }
}

// MFMA 16x16x32 fragment from swizzled LDS tile [*][64].
__device__ __forceinline__ f16x8 frag_ld(const u16* lds, int r0, int kc, int lane){
  int r = r0 + (lane&15);
  int c = (kc + (lane>>4)) ^ (r&7);
  return *(const f16x8*)(lds + r*64 + c*8);
}

// ---- 128x128-tile GEMM. OUTMODE 0: relu+fp16. 1: fp32. 2: fp16.
template<int AMAP, int BMAP, int OUTMODE>
__global__ __launch_bounds__(256,3) void gemm128(const void* A, const void* Bt, void* C,
    const float* __restrict__ biasf, const int* __restrict__ flag,
    int K, int lda, int ldb, int ldc, int t0, int amode, int bmode){
  int m=*flag;
  int am = amode<0 ? m : amode;
  int bm_ = bmode<0 ? m : bmode;
  __shared__ u16 As[128*64];
  __shared__ u16 Bs[128*64];
  int tid=threadIdx.x, lane=tid&63, w=tid>>6;
  int bm=blockIdx.y*128, bn=blockIdx.x*128;
  int wm=(w&1)*64, wn=(w>>1)*64;
  f32x4 acc[4][4];
#pragma unroll
  for(int i=0;i<4;i++)
#pragma unroll
    for(int j=0;j<4;j++) acc[i][j]=(f32x4)(0.f);
  for(int k0=0;k0<K;k0+=64){
    stage<128,AMAP>(A , am,  lda, k0, bm, t0, As, tid);
    stage<128,BMAP>(Bt, bm_, ldb, k0, bn, t0, Bs, tid);
    __syncthreads();
#pragma unroll
    for(int kk=0;kk<2;kk++){
      f16x8 af[4], bq[4];
#pragma unroll
      for(int i=0;i<4;i++) af[i]=frag_ld(As, wm+i*16, kk*4, lane);
#pragma unroll
      for(int j=0;j<4;j++) bq[j]=frag_ld(Bs, wn+j*16, kk*4, lane);
#pragma unroll
      for(int i=0;i<4;i++)
#pragma unroll
        for(int j=0;j<4;j++)
          acc[i][j]=__builtin_amdgcn_mfma_f32_16x16x32_f16(af[i],bq[j],acc[i][j],0,0,0);
    }
    __syncthreads();
  }
  int rl=lane>>4, cl=lane&15;
#pragma unroll
  for(int j=0;j<4;j++){
    int col=bn+wn+j*16+cl;
    float bb=biasf[col];
#pragma unroll
    for(int i=0;i<4;i++){
#pragma unroll
      for(int r=0;r<4;r++){
        int row=bm+wm+i*16+rl*4+r;
        float v=acc[i][j][r]+bb;
        if(OUTMODE==0){ v=fmaxf(v,0.f); ((u16*)C)[(size_t)row*ldc+col]=f2h(v); }
        else if(OUTMODE==2){ ((u16*)C)[(size_t)row*ldc+col]=f2h(v); }
        else { ((float*)C)[(size_t)row*ldc+col]=v; }
      }
    }
  }
}

// ---- persistent chunk-LSTM (r15-verified; hh FULL [B][S+1][H], seed slot 0, step t -> t+1).
__global__ __launch_bounds__(512,2) void lstm_persist(u16* __restrict__ hh,
        const u16* __restrict__ Whhp, const u16* __restrict__ xgp,
        float* __restrict__ cst, int* __restrict__ cntc, int tbase){
  __shared__ u16 As[16*2048];     // 64 KB: 16 k-tiles [32][64], XOR-swizzled
  __shared__ float gs[32*132];    // 16.9 KB, stride 132
  int tid=threadIdx.x, lane=tid&63, w=tid>>6;
  int grp=blockIdx.x&7, ci=blockIdx.x>>3;
  int bm=grp*32, bn=ci*128;
  int* flags = cntc + grp*64;

  f16x8 bw[32];
#pragma unroll
  for(int t=0;t<32;t++){
    int p = bn + w*16 + (lane&15);
    int k = t*32 + (lane>>4)*8;
    bw[t]=*(const f16x8*)(Whhp + (size_t)p*H_ + k);
  }
#pragma unroll
  for(int t=0;t<32;t++) asm volatile("" : "+a"(bw[t]));

  int rl0=tid>>5, rl1=(tid+512)>>5, u0=tid&31;
  int gu=(bn>>2)+u0;
  float c0=cst[(size_t)(bm+rl0)*H_+gu];
  float c1=cst[(size_t)(bm+rl1)*H_+gu];

  for(int dt=0;dt<CH_;dt++){
    f16x4 xv0=*(const f16x4*)(xgp + ((size_t)(bm+rl0)*CH_+dt)*G_ + bn + u0*4);
    f16x4 xv1=*(const f16x4*)(xgp + ((size_t)(bm+rl1)*CH_+dt)*G_ + bn + u0*4);
    if(dt) bar_flags32(flags, tbase+dt, ci, lane, w);
    const u16* hbase = hh + (size_t)(tbase+dt)*H_;   // read slot tbase+dt
    {
      u32x4 tmp[4];
#pragma unroll
      for(int i=0;i<4;i++){
        int s=tid+i*512, kt=s>>8, r=(s>>3)&31, gc=s&7;
        tmp[i]=*(const u32x4*)(hbase + (size_t)(bm+r)*(SP1*H_) + kt*64 + gc*8);
      }
#pragma unroll
      for(int i=0;i<4;i++){
        int s=tid+i*512, kt=s>>8, r=(s>>3)&31, gc=s&7, lc=gc^(r&7);
        *(u32x4*)(As + kt*2048 + r*64 + lc*8)=tmp[i];
      }
    }
    __syncthreads();
    u32x4 tmp2[4];
#pragma unroll
    for(int i=0;i<4;i++){
      int s=tid+(i+4)*512, kt=s>>8, r=(s>>3)&31, gc=s&7;
      tmp2[i]=*(const u32x4*)(hbase + (size_t)(bm+r)*(SP1*H_) + kt*64 + gc*8);
    }
    f32x4 acc0=(f32x4)(0.f), acc1=(f32x4)(0.f);
#pragma unroll
    for(int t=0;t<16;t++){
      int kt=t>>1, kk=t&1;
      f16x8 af0=frag_ld(As+kt*2048, 0,  kk*4, lane);
      f16x8 af1=frag_ld(As+kt*2048, 16, kk*4, lane);
      acc0=__builtin_amdgcn_mfma_f32_16x16x32_f16(af0,bw[t],acc0,0,0,0);
      acc1=__builtin_amdgcn_mfma_f32_16x16x32_f16(af1,bw[t],acc1,0,0,0);
    }
#pragma unroll
    for(int i=0;i<4;i++){
      int s=tid+(i+4)*512, kt=s>>8, r=(s>>3)&31, gc=s&7, lc=gc^(r&7);
      *(u32x4*)(As + kt*2048 + r*64 + lc*8)=tmp2[i];
    }
    __syncthreads();
#pragma unroll
    for(int t=16;t<32;t++){
      int kt=t>>1, kk=t&1;
      f16x8 af0=frag_ld(As+kt*2048, 0,  kk*4, lane);
      f16x8 af1=frag_ld(As+kt*2048, 16, kk*4, lane);
      acc0=__builtin_amdgcn_mfma_f32_16x16x32_f16(af0,bw[t],acc0,0,0,0);
      acc1=__builtin_amdgcn_mfma_f32_16x16x32_f16(af1,bw[t],acc1,0,0,0);
    }
#pragma unroll
    for(int r=0;r<4;r++){
      gs[(   (lane>>4)*4+r)*132 + w*16+(lane&15)]=acc0[r];
      gs[(16+(lane>>4)*4+r)*132 + w*16+(lane&15)]=acc1[r];
    }
    __syncthreads();
    {
      float4 gv=*(const float4*)&gs[rl0*132+u0*4];
      float ii=1.f/(1.f+__expf(-(gv.x+(float)xv0[0])));
      float ff=1.f/(1.f+__expf(-(gv.y+(float)xv0[1])));
      float gg=1.f-2.f/(__expf(2.f*(gv.z+(float)xv0[2]))+1.f);
      float oo=1.f/(1.f+__expf(-(gv.w+(float)xv0[3])));
      c0=ff*c0+ii*gg;
      float th=1.f-2.f/(__expf(2.f*c0)+1.f);
      store_c2(hh + ((size_t)(bm+rl0)*SP1 + tbase+dt+1)*H_ + gu, f2h(oo*th));
    }
    {
      float4 gv=*(const float4*)&gs[rl1*132+u0*4];
      float ii=1.f/(1.f+__expf(-(gv.x+(float)xv1[0])));
      float ff=1.f/(1.f+__expf(-(gv.y+(float)xv1[1])));
      float gg=1.f-2.f/(__expf(2.f*(gv.z+(float)xv1[2]))+1.f);
      float oo=1.f/(1.f+__expf(-(gv.w+(float)xv1[3])));
      c1=ff*c1+ii*gg;
      float th=1.f-2.f/(__expf(2.f*c1)+1.f);
      store_c2(hh + ((size_t)(bm+rl1)*SP1 + tbase+dt+1)*H_ + gu, f2h(oo*th));
    }
  }
  cst[(size_t)(bm+rl0)*H_+gu]=c0;
  cst[(size_t)(bm+rl1)*H_+gu]=c1;
}

// ---- fallback per-step LSTM (low-ws tier)
__global__ __launch_bounds__(256,2) void lstm_step(u16* __restrict__ hh, int slotAbs, int dt,
        const void* __restrict__ Whh, const u16* __restrict__ xg,
        float* __restrict__ cst, const int* __restrict__ flag){
  int m=*flag;
  __shared__ u16 As[64*64];
  __shared__ u16 Bs[64*64];
  __shared__ float gs[64*64];
  int tid=threadIdx.x, lane=tid&63, w=tid>>6;
  int bm=blockIdx.y*64, bn=blockIdx.x*64;
  int wm=(w&1)*32, wn=(w>>1)*32;
  f32x4 acc[2][2];
#pragma unroll
  for(int i=0;i<2;i++)
#pragma unroll
    for(int j=0;j<2;j++) acc[i][j]=(f32x4)(0.f);
  for(int k0=0;k0<H_;k0+=64){
    stage<64,0>(hh + (size_t)slotAbs*H_, 2, SP1*H_, k0, bm, 0, As, tid);
    stage<64,1>(Whh,                     m, H_,     k0, bn, 0, Bs, tid);
    __syncthreads();
#pragma unroll
    for(int kk=0;kk<2;kk++){
      f16x8 af[2], bq[2];
#pragma unroll
      for(int i=0;i<2;i++) af[i]=frag_ld(As, wm+i*16, kk*4, lane);
#pragma unroll
      for(int j=0;j<2;j++) bq[j]=frag_ld(Bs, wn+j*16, kk*4, lane);
#pragma unroll
      for(int i=0;i<2;i++)
#pragma unroll
        for(int j=0;j<2;j++)
          acc[i][j]=__builtin_amdgcn_mfma_f32_16x16x32_f16(af[i],bq[j],acc[i][j],0,0,0);
    }
    __syncthreads();
  }
  int rl=lane>>4, cl=lane&15;
#pragma unroll
  for(int j=0;j<2;j++){
    int coll=wn+j*16+cl;
#pragma unroll
    for(int i=0;i<2;i++){
#pragma unroll
      for(int r=0;r<4;r++){
        int rowl=wm+i*16+rl*4+r;
        float xv=(float)((const _Float16*)xg)[((size_t)(bm+rowl)*CH_+dt)*G_ + bn+coll];
        gs[rowl*64+coll]=acc[i][j][r] + xv;
      }
    }
  }
  __syncthreads();
#pragma unroll
  for(int p=0;p<4;p++){
    int idx=p*256+tid;
    int rowl=idx>>4, u=idx&15;
    float4 gv = *(const float4*)&gs[rowl*64+u*4];
    float ii=1.f/(1.f+__expf(-gv.x));
    float ff=1.f/(1.f+__expf(-gv.y));
    float gg=1.f-2.f/(__expf(2.f*gv.z)+1.f);
    float oo=1.f/(1.f+__expf(-gv.w));
    int gb=bm+rowl;
    int gu=(bn>>2)+u;
    size_t ci=(size_t)gb*H_+gu;
    float cn=ff*cst[ci]+ii*gg;
    cst[ci]=cn;
    float th=1.f-2.f/(__expf(2.f*cn)+1.f);
    hh[((size_t)gb*SP1 + slotAbs+1)*H_ + gu]=f2h(oo*th);
  }
}

// ---- heads as MFMA GEMM + fused log-softmax (r15-verified).
__global__ __launch_bounds__(512,1) void heads_gemm(const u16* __restrict__ hh,
      const u16* __restrict__ WH, const float* __restrict__ blf,
      const int* __restrict__ acts, void* __restrict__ out, const int* __restrict__ flag){
  int m=*flag;
  __shared__ u16 Bs[16*2048];
  __shared__ u16 As[128*64];
  __shared__ float gs[128*36];
  int tid=threadIdx.x, lane=tid&63, w=tid>>6;
  int bm=blockIdx.x*128;
#pragma unroll
  for(int i=0;i<8;i++){
    int s=tid+i*512;
    int kt=s>>8, r=(s>>3)&31, gc=s&7, lc=gc^(r&7);
    *(f16x8*)(Bs+kt*2048+r*64+lc*8) = *(const f16x8*)(WH + (size_t)r*H_ + kt*64 + gc*8);
  }
  f32x4 acc0=(f32x4)(0.f), acc1=(f32x4)(0.f);
  for(int kt=0;kt<16;kt++){
#pragma unroll
    for(int i=0;i<2;i++){
      int s0=i*512+(w<<6), s=s0+lane;
      int r=s>>3, gc=(s&7)^(r&7);
      int rg=bm+r;
      const u16* src=hh + ((size_t)(rg>>7)*SP1 + (rg&127)+1)*H_ + kt*64 + gc*8;
      u16* dst=As + s0*8;
      __builtin_amdgcn_global_load_lds((const __attribute__((address_space(1))) unsigned int*)src,
                                       (__attribute__((address_space(3))) unsigned int*)dst,
                                       16, 0, 0);
    }
    __syncthreads();
#pragma unroll
    for(int kk=0;kk<2;kk++){
      f16x8 af=frag_ld(As, w*16, kk*4, lane);
      f16x8 b0=frag_ld(Bs+kt*2048, 0,  kk*4, lane);
      f16x8 b1=frag_ld(Bs+kt*2048, 16, kk*4, lane);
      acc0=__builtin_amdgcn_mfma_f32_16x16x32_f16(af,b0,acc0,0,0,0);
      acc1=__builtin_amdgcn_mfma_f32_16x16x32_f16(af,b1,acc1,0,0,0);
    }
    __syncthreads();
  }
#pragma unroll
  for(int r=0;r<4;r++){
    gs[(w*16+(lane>>4)*4+r)*36 + (lane&15)]      = acc0[r];
    gs[(w*16+(lane>>4)*4+r)*36 + 16 + (lane&15)] = acc1[r];
  }
  __syncthreads();
  if(tid<128){
    int rg=bm+tid;
    float lg[18];
#pragma unroll
    for(int j=0;j<18;j++) lg[j]=gs[tid*36+j]+blf[j];
    float value=gs[tid*36+18]+blf[18];
    float mx=lg[0];
#pragma unroll
    for(int j=1;j<18;j++) mx=fmaxf(mx,lg[j]);
    float se=0.f, s1=0.f;
#pragma unroll
    for(int j=0;j<18;j++){ float e=__expf(lg[j]-mx); se+=e; s1+=e*(lg[j]-mx); }
    float lse=__logf(se);
    int a=acts[rg];
    float la=0.f;
#pragma unroll
    for(int j=0;j<18;j++) la = (j==a) ? lg[j] : la;
    float lp=la-mx-lse;
    float ent=lse - s1/se;
    if(m){
      ((float*)out)[rg]=lp; ((float*)out)[M_+rg]=ent; ((float*)out)[2*M_+rg]=value;
    } else {
      ((u16*)out)[rg]=f2bf(lp); ((u16*)out)[M_+rg]=f2bf(ent); ((u16*)out)[2*M_+rg]=f2bf(value);
    }
  }
}

// ---- fallback heads (no-WH tier)
__global__ __launch_bounds__(256,2) void heads_full(const u16* __restrict__ hh,
      const void* __restrict__ Wl, const void* __restrict__ Wv,
      const float* __restrict__ blf, const int* __restrict__ acts,
      void* __restrict__ out, const int* __restrict__ flag){
  int m=*flag;
  int rg = blockIdx.x*4 + (threadIdx.x>>6);
  int lane = threadIdx.x & 63;
  int b=rg>>7, t=rg&(S_-1);
  const u16* h = hh + ((size_t)b*SP1 + t+1)*H_;
  f16x8 h0=*(const f16x8*)(h + lane*16), h1=*(const f16x8*)(h + lane*16 + 8);
  float hv[16];
#pragma unroll
  for(int k=0;k<8;k++){ hv[k]=(float)h0[k]; hv[8+k]=(float)h1[k]; }
  float dots[19];
#pragma unroll
  for(int j=0;j<19;j++){
    const void* wrow = (j<18) ? Wl : Wv;
    size_t roff = (j<18) ? (size_t)j*H_ : 0;
    float wv_[16];
    if(m){
      const float* f=(const float*)wrow + roff + lane*16;
      float4 a=*(const float4*)f, b2=*(const float4*)(f+4), c=*(const float4*)(f+8), d=*(const float4*)(f+12);
      wv_[0]=a.x;wv_[1]=a.y;wv_[2]=a.z;wv_[3]=a.w; wv_[4]=b2.x;wv_[5]=b2.y;wv_[6]=b2.z;wv_[7]=b2.w;
      wv_[8]=c.x;wv_[9]=c.y;wv_[10]=c.z;wv_[11]=c.w; wv_[12]=d.x;wv_[13]=d.y;wv_[14]=d.z;wv_[15]=d.w;
    } else {
      const u16* ub=(const u16*)wrow + roff + lane*16;
      s16x8 w0=*(const s16x8*)ub, w1=*(const s16x8*)(ub+8);
#pragma unroll
      for(int k=0;k<8;k++){ wv_[k]=bf2f((u16)w0[k]); wv_[8+k]=bf2f((u16)w1[k]); }
    }
    float d=0.f;
#pragma unroll
    for(int k=0;k<16;k++) d += hv[k]*wv_[k];
#pragma unroll
    for(int mm=1;mm<64;mm<<=1) d += __shfl_xor(d, mm, 64);
    dots[j]=d;
  }
  float lg[18];
#pragma unroll
  for(int j=0;j<18;j++) lg[j]=dots[j]+blf[j];
  float value=dots[18]+blf[18];
  float mx=lg[0];
#pragma unroll
  for(int j=1;j<18;j++) mx=fmaxf(mx,lg[j]);
  float se=0.f, s1=0.f;
#pragma unroll
  for(int j=0;j<18;j++){ float e=__expf(lg[j]-mx); se+=e; s1+=e*(lg[j]-mx); }
  float lse=__logf(se);
  int a=acts[rg];
  float la=0.f;
#pragma unroll
  for(int j=0;j<18;j++) la = (j==a) ? lg[j] : la;
  float lp=la-mx-lse;
  float ent=lse - s1/se;
  if(lane==0){
    if(m){
      ((float*)out)[rg]=lp; ((float*)out)[M_+rg]=ent; ((float*)out)[2*M_+rg]=value;
    } else {
      ((u16*)out)[rg]=f2bf(lp); ((u16*)out)[M_+rg]=f2bf(ent); ((u16*)out)[2*M_+rg]=f2bf(value);
    }
  }
}

// ---- dtype detect
__global__ void detect(const u16* __restrict__ obs_w, int* __restrict__ flag){
  __shared__ float red[256];
  float mx=0.f;
  for(int i=threadIdx.x;i<4096;i+=256) mx=fmaxf(mx,fabsf(bf2f(obs_w[i])));
  red[threadIdx.x]=mx; __syncthreads();
  for(int s=128;s>0;s>>=1){
    if(threadIdx.x<s) red[threadIdx.x]=fmaxf(red[threadIdx.x],red[threadIdx.x+s]);
    __syncthreads();
  }
  if(threadIdx.x==0) *flag=(red[0]>1e4f)?1:0;
}

// ---- prep
__global__ void prep(const void* bih, const void* bhh, const void* b1, const void* bl, const void* bv,
                     const void* cx, const void* hx,
                     float* biasg, float* b1f, float* blf, float* cst, u16* hh,
                     int* cnt, const int* __restrict__ flag){
  int m=*flag;
  size_t i=(size_t)blockIdx.x*256+threadIdx.x;
  if(i<G_){ size_t rm=(i&3)*H_+(i>>2); biasg[i]=ldf(bih,rm,m)+ldf(bhh,rm,m); return; }
  i-=G_;
  if(i<H_){ b1f[i]=ldf(b1,i,m); return; }
  i-=H_;
  if(i<19){ blf[i]=(i<18)?ldf(bl,i,m):ldf(bv,0,m); return; }
  i-=19;
  if(i<512){ cnt[i]=0; return; }
  i-=512;
  if(i<(size_t)B_*H_){ cst[i]=ldf(cx,i,m); return; }
  i-=(size_t)B_*H_;
  if(i<(size_t)B_*H_){
    size_t b=i>>10, k=i&1023;
    hh[b*(SP1*H_) + k]=f2h(ldf(hx,i,m));   // seed at slot 0
  }
}

// ---- weight pre-conversion
__global__ void convw(const void* W1, const void* Wih, const void* Whh,
                      const void* Wl, const void* Wv,
                      u16* W1h, u16* Wihp, u16* Whhp, u16* WH,
                      const int* __restrict__ flag){
  int m=*flag;
  size_t i=((size_t)blockIdx.x*256+threadIdx.x)*8;
  const size_t n1=(size_t)H_*F_, n2=(size_t)G_*H_, n3=(size_t)32*H_;
  if(i<n1){ *(f16x8*)(W1h+i)=load8_h(W1,i,m); return; }
  i-=n1;
  if(i<n2){ size_t p=i>>10, c=i&1023; size_t sr=(p&3)*H_+(p>>2);
            *(f16x8*)(Wihp+i)=load8_h(Wih, sr*H_+c, m); return; }
  i-=n2;
  if(i<n2){ size_t p=i>>10, c=i&1023; size_t sr=(p&3)*H_+(p>>2);
            *(f16x8*)(Whhp+i)=load8_h(Whh, sr*H_+c, m); return; }
  i-=n2;
  if(i<n3){
    size_t j=i>>10, c=i&1023;
    f16x8 v;
    if(j<18)      v=load8_h(Wl, j*H_+c, m);
    else if(j==18) v=load8_h(Wv, c, m);
    else{ for(int k=0;k<8;k++) v[k]=(_Float16)0.f; }
    *(f16x8*)(WH+i)=v;
  }
}
__global__ void convobs(const void* obs, u16* obsh, const int* __restrict__ flag){
  int m=*flag;
  size_t i=((size_t)blockIdx.x*256+threadIdx.x)*8;
  if(i<(size_t)M_*F_) *(f16x8*)(obsh+i)=load8_h(obs,i,m);
}

extern "C" void kernel_launch(void* const* d_in, const int* in_sizes, int n_in,
                              void* d_out, int out_size, void* d_ws, size_t ws_size,
                              hipStream_t stream){
  const void* obs=d_in[0];
  const void* hx =d_in[1];
  const void* cx =d_in[2];
  const int* acts=(const int*)d_in[3];
  const void* W1 =d_in[4];
  const void* b1 =d_in[5];
  const void* Wih=d_in[6];
  const void* bih=d_in[7];
  const void* Whh=d_in[8];
  const void* bhh=d_in[9];
  const void* Wv =d_in[10];
  const void* bv =d_in[11];
  const void* Wl =d_in[12];
  const void* bl =d_in[13];

  char* w=(char*)d_ws;
  auto alloc=[&](size_t n){ char* p=w; w+=((n+255)&~(size_t)255); return p; };
  int*   flag =(int*)alloc(4);
  int*   cnt  =(int*)alloc(512*4);
  float* biasg=(float*)alloc((size_t)G_*4);
  float* b1f  =(float*)alloc((size_t)H_*4);
  float* blf  =(float*)alloc(32*4);
  float* cst  =(float*)alloc((size_t)B_*H_*4);
  u16*   hh   =(u16*)alloc((size_t)B_*SP1*H_*2);   // 67.6 MB
  u16*   xc   =(u16*)alloc((size_t)CR_*H_*2);      // 16.8 MB
  u16*   xg   =(u16*)alloc((size_t)CR_*G_*2);      // 67 MB fp16 xg chunk (CH_=32)
  // tiers
  size_t nW=((size_t)H_*F_ + 2*(size_t)G_*H_ + 32*(size_t)H_)*2 + 1024;
  bool pathW = ((size_t)(w-(char*)d_ws) + nW) <= ws_size;
  u16 *W1h=0,*Wihp=0,*Whhp=0,*WH=0;
  if(pathW){ W1h=(u16*)alloc((size_t)H_*F_*2); Wihp=(u16*)alloc((size_t)G_*H_*2);
             Whhp=(u16*)alloc((size_t)G_*H_*2); WH=(u16*)alloc((size_t)32*H_*2); }
  size_t nXC=(size_t)M_*H_*2 + 256;
  bool pathXC = pathW && (((size_t)(w-(char*)d_ws) + nXC) <= ws_size);
  u16* xcf=0; if(pathXC) xcf=(u16*)alloc((size_t)M_*H_*2);
  size_t nO=(size_t)M_*F_*2 + 256;
  bool pathO = pathXC && (((size_t)(w-(char*)d_ws) + nO) <= ws_size);
  u16* obsh=0; if(pathO) obsh=(u16*)alloc((size_t)M_*F_*2);

  detect<<<1,256,0,stream>>>((const u16*)obs, flag);
  {
    int total=G_+H_+19+512+B_*H_+B_*H_;
    prep<<<(total+255)/256,256,0,stream>>>(bih,bhh,b1,bl,bv,cx,hx, biasg,b1f,blf,cst,hh,cnt, flag);
  }
  if(pathW){
    size_t n=((size_t)H_*F_+2*(size_t)G_*H_+32*(size_t)H_)/8;
    convw<<<(int)((n+255)/256),256,0,stream>>>(W1,Wih,Whh,Wl,Wv, W1h,Wihp,Whhp,WH, flag);
  }
  if(pathO){
    size_t n=(size_t)M_*F_/8;
    convobs<<<(int)((n+255)/256),256,0,stream>>>(obs, obsh, flag);
  }
  if(pathXC){
    gemm128<0,0,0><<<dim3(H_/128, M_/128),256,0,stream>>>(
        pathO?(const void*)obsh:obs, pathW?(const void*)W1h:W1, xcf, b1f, flag,
        F_, F_, F_, H_, 0, pathO?2:-1, pathW?2:-1);
  }

  const int NC=S_/CH_;
  for(int c=0;c<NC;c++){
    int t0=c*CH_;
    if(!pathXC){
      gemm128<2,0,0><<<dim3(H_/128, CR_/128),256,0,stream>>>(
          obs, pathW?(const void*)W1h:W1, xc, b1f, flag, F_, F_, F_, H_, t0, -1, pathW?2:-1);
    }
    if(pathXC)
      gemm128<2,0,2><<<dim3(G_/128, CR_/128),256,0,stream>>>(
          xcf, Wihp, xg, biasg, flag, H_, H_, H_, G_, t0, 2, 2);
    else if(pathW)
      gemm128<0,0,2><<<dim3(G_/128, CR_/128),256,0,stream>>>(
          xc, Wihp, xg, biasg, flag, H_, H_, H_, G_, 0, 2, 2);
    else
      gemm128<0,1,2><<<dim3(G_/128, CR_/128),256,0,stream>>>(
          xc, Wih, xg, biasg, flag, H_, H_, H_, G_, 0, 2, -1);

    if(pathW)
      lstm_persist<<<256,512,0,stream>>>(hh, Whhp, xg, cst, cnt, t0);
    else
      for(int dt=0;dt<CH_;dt++)
        lstm_step<<<dim3(G_/64, B_/64),256,0,stream>>>(hh, t0+dt, dt, Whh, xg, cst, flag);
  }

  if(pathW)
    heads_gemm<<<dim3(M_/128),512,0,stream>>>(hh, WH, blf, acts, d_out, flag);
  else
    heads_full<<<dim3(M_/4),256,0,stream>>>(hh, Wl, Wv, blf, acts, d_out, flag);
}

// Round 19
// 1029.431 us; speedup vs baseline: 1.2594x; 1.0035x over previous
//
#include <hip/hip_runtime.h>

#define B_ 256
#define S_ 128
#define SP1 (S_+1)
#define F_ 512
#define H_ 1024
#define A_ 18
#define M_ (B_*S_)      // 32768 output rows (b*S+s)
#define G_ (4*H_)       // 4096 gate cols, permuted unit-major: p = unit*4 + {i,f,g,o}
#define CH_ 32          // timesteps per chunk (4 chunks)
#define CR_ (B_*CH_)    // 8192 rows per chunk

typedef unsigned short u16;
typedef __attribute__((ext_vector_type(8))) _Float16 f16x8;  // 8 fp16 = 4 VGPR
typedef __attribute__((ext_vector_type(4))) _Float16 f16x4;
typedef __attribute__((ext_vector_type(8))) short   s16x8;
typedef __attribute__((ext_vector_type(4))) float f32x4;
typedef __attribute__((ext_vector_type(4))) unsigned int u32x4;

__device__ __forceinline__ float bf2f(u16 u){
  union{unsigned int i; float f;} v; v.i=((unsigned int)u)<<16; return v.f;
}
__device__ __forceinline__ u16 f2bf(float f){
  unsigned int i=__float_as_uint(f);
  unsigned int r=(i+0x7fffu+((i>>16)&1u))>>16;   // RNE
  return (u16)r;
}
__device__ __forceinline__ u16 f2h(float f){
  _Float16 h=(_Float16)f;
  union{_Float16 h; u16 u;} v; v.h=h; return v.u;
}
__device__ __forceinline__ float ldf(const void* p, size_t i, int m){
  return m ? ((const float*)p)[i] : bf2f(((const u16*)p)[i]);
}
// load 8 logical floats -> fp16x8. mode 0: bf16 src, 1: fp32 src, 2: raw fp16 src.
__device__ __forceinline__ f16x8 load8_h(const void* base, size_t off, int m){
  f16x8 v;
  if(m==2) return *(const f16x8*)((const u16*)base + off);
  if(m==1){
    const float* f=(const float*)base + off;
    float4 a=*(const float4*)f; float4 b=*(const float4*)(f+4);
    v[0]=(_Float16)a.x; v[1]=(_Float16)a.y; v[2]=(_Float16)a.z; v[3]=(_Float16)a.w;
    v[4]=(_Float16)b.x; v[5]=(_Float16)b.y; v[6]=(_Float16)b.z; v[7]=(_Float16)b.w;
    return v;
  }
  s16x8 w=*(const s16x8*)((const u16*)base + off);
#pragma unroll
  for(int k=0;k<8;k++) v[k]=(_Float16)bf2f((u16)w[k]);
  return v;
}

// ---- coherent (cross-XCD, LLC-routed) accesses: bypass L1+L2 via sc0 sc1.
__device__ __forceinline__ u32x4 load_c16(const void* p){
  u32x4 r;
  asm volatile("global_load_dwordx4 %0, %1, off sc0 sc1" : "=v"(r) : "v"(p));
  return r;
}
__device__ __forceinline__ void store_c2(u16* p, u16 v){
  unsigned int vv=v;
  asm volatile("global_store_short %0, %1, off sc0 sc1" :: "v"(p), "v"(vv) : "memory");
}
__device__ __forceinline__ int load_c4(const int* p){
  int r;
  asm volatile("global_load_dword %0, %1, off sc0 sc1" : "=v"(r) : "v"(p));
  return r;
}
__device__ __forceinline__ void store_c4(int* p, int v){
  asm volatile("global_store_dword %0, %1, off sc0 sc1" :: "v"(p), "v"(v) : "memory");
}

// ---- store-flag group barrier (32 blocks)
__device__ __forceinline__ void bar_flags32(int* flags, int target, int gi, int lane, int w){
  asm volatile("s_waitcnt vmcnt(0)" ::: "memory");   // own h stores at LLC
  __syncthreads();
  if(w==0){
    if(lane==0) store_c4(flags+gi, target);
    while(true){
      int v=load_c4(flags+(lane&31));
      asm volatile("s_waitcnt vmcnt(0)" ::: "memory");
      if(__all(v>=target)) break;
      __builtin_amdgcn_s_sleep(1);
    }
  }
  __syncthreads();
}

// ---- Stage ROWS x 64 fp16 tile into LDS [ROWS][64], XOR-swizzled (256-thr blocks).
// MAP 0: row=rowoff+r. MAP 1: gate-permute. MAP 2: x rows for chunk (rg=b*CH_+dt).
template<int ROWS, int MAP>
__device__ __forceinline__ void stage(const void* base, int mode, int lda, int k0,
                                      int rowoff, int t0, u16* lds, int tid){
  if(mode==2){
    constexpr int NI=(ROWS*8)/256;
    int wv=tid>>6, l=tid&63;
#pragma unroll
    for(int i=0;i<NI;i++){
      int s0=i*256+(wv<<6), s=s0+l;
      int r=s>>3, gc=(s&7)^(r&7);
      int p=rowoff+r, sr;
      if(MAP==0)      sr=p;
      else if(MAP==1) sr=(p&3)*H_+(p>>2);
      else            sr=(p/CH_)*S_+t0+(p%CH_);
      const u16* src=(const u16*)base + (size_t)sr*lda + k0 + gc*8;
      u16* dst=lds + s0*8;             // wave-uniform; HW adds lane*16B
      __builtin_amdgcn_global_load_lds((const __attribute__((address_space(1))) unsigned int*)src,
                                       (__attribute__((address_space(3))) unsigned int*)dst,
                                       16, 0, 0);
    }
  } else {
#pragma unroll
    for(int s0=tid; s0<ROWS*8; s0+=256){
      int r=s0>>3, gc=s0&7, lc=gc^(r&7);
      int p=rowoff+r, sr;
      if(MAP==0)      sr=p;
      else if(MAP==1) sr=(p&3)*H_+(p>>2);
      else            sr=(p/CH_)*S_+t0+(p%CH_);
      f16x8 v=load8_h(base, (size_t)sr*lda + k0 + gc*8, mode);
      *(f16x8*)(lds + r*64 + lc*8)=v;
    }
  }
}

// MFMA 16x16x32 fragment from swizzled LDS tile [*][64].
__device__ __forceinline__ f16x8 frag_ld(const u16* lds, int r0, int kc, int lane){
  int r = r0 + (lane&15);
  int c = (kc + (lane>>4)) ^ (r&7);
  return *(const f16x8*)(lds + r*64 + c*8);
}

// ---- 128x128-tile GEMM. OUTMODE 0: relu+fp16. 1: fp32. 2: fp16.
template<int AMAP, int BMAP, int OUTMODE>
__global__ __launch_bounds__(256,3) void gemm128(const void* A, const void* Bt, void* C,
    const float* __restrict__ biasf, const int* __restrict__ flag,
    int K, int lda, int ldb, int ldc, int t0, int amode, int bmode){
  int m=*flag;
  int am = amode<0 ? m : amode;
  int bm_ = bmode<0 ? m : bmode;
  __shared__ u16 As[128*64];
  __shared__ u16 Bs[128*64];
  int tid=threadIdx.x, lane=tid&63, w=tid>>6;
  int bm=blockIdx.y*128, bn=blockIdx.x*128;
  int wm=(w&1)*64, wn=(w>>1)*64;
  f32x4 acc[4][4];
#pragma unroll
  for(int i=0;i<4;i++)
#pragma unroll
    for(int j=0;j<4;j++) acc[i][j]=(f32x4)(0.f);
  for(int k0=0;k0<K;k0+=64){
    stage<128,AMAP>(A , am,  lda, k0, bm, t0, As, tid);
    stage<128,BMAP>(Bt, bm_, ldb, k0, bn, t0, Bs, tid);
    __syncthreads();
#pragma unroll
    for(int kk=0;kk<2;kk++){
      f16x8 af[4], bq[4];
#pragma unroll
      for(int i=0;i<4;i++) af[i]=frag_ld(As, wm+i*16, kk*4, lane);
#pragma unroll
      for(int j=0;j<4;j++) bq[j]=frag_ld(Bs, wn+j*16, kk*4, lane);
#pragma unroll
      for(int i=0;i<4;i++)
#pragma unroll
        for(int j=0;j<4;j++)
          acc[i][j]=__builtin_amdgcn_mfma_f32_16x16x32_f16(af[i],bq[j],acc[i][j],0,0,0);
    }
    __syncthreads();
  }
  int rl=lane>>4, cl=lane&15;
#pragma unroll
  for(int j=0;j<4;j++){
    int col=bn+wn+j*16+cl;
    float bb=biasf[col];
#pragma unroll
    for(int i=0;i<4;i++){
#pragma unroll
      for(int r=0;r<4;r++){
        int row=bm+wm+i*16+rl*4+r;
        float v=acc[i][j][r]+bb;
        if(OUTMODE==0){ v=fmaxf(v,0.f); ((u16*)C)[(size_t)row*ldc+col]=f2h(v); }
        else if(OUTMODE==2){ ((u16*)C)[(size_t)row*ldc+col]=f2h(v); }
        else { ((float*)C)[(size_t)row*ldc+col]=v; }
      }
    }
  }
}

// ---- persistent chunk-LSTM (r18-verified; xg prefetch moved AFTER the barrier so
// the arrival-path vmcnt(0) drains only h stores, not HBM xg loads).
__global__ __launch_bounds__(512,2) void lstm_persist(u16* __restrict__ hh,
        const u16* __restrict__ Whhp, const u16* __restrict__ xgp,
        float* __restrict__ cst, int* __restrict__ cntc, int tbase){
  __shared__ u16 As[16*2048];     // 64 KB: 16 k-tiles [32][64], XOR-swizzled
  __shared__ float gs[32*132];    // 16.9 KB, stride 132
  int tid=threadIdx.x, lane=tid&63, w=tid>>6;
  int grp=blockIdx.x&7, ci=blockIdx.x>>3;
  int bm=grp*32, bn=ci*128;
  int* flags = cntc + grp*64;

  f16x8 bw[32];
#pragma unroll
  for(int t=0;t<32;t++){
    int p = bn + w*16 + (lane&15);
    int k = t*32 + (lane>>4)*8;
    bw[t]=*(const f16x8*)(Whhp + (size_t)p*H_ + k);
  }
#pragma unroll
  for(int t=0;t<32;t++) asm volatile("" : "+a"(bw[t]));

  int rl0=tid>>5, rl1=(tid+512)>>5, u0=tid&31;
  int gu=(bn>>2)+u0;
  float c0=cst[(size_t)(bm+rl0)*H_+gu];
  float c1=cst[(size_t)(bm+rl1)*H_+gu];

  for(int dt=0;dt<CH_;dt++){
    if(dt) bar_flags32(flags, tbase+dt, ci, lane, w);
    // xg prefetch AFTER barrier: overlaps stage+MFMA, off the arrival critical path
    f16x4 xv0=*(const f16x4*)(xgp + ((size_t)(bm+rl0)*CH_+dt)*G_ + bn + u0*4);
    f16x4 xv1=*(const f16x4*)(xgp + ((size_t)(bm+rl1)*CH_+dt)*G_ + bn + u0*4);
    const u16* hbase = hh + (size_t)(tbase+dt)*H_;   // read slot tbase+dt
    {
      u32x4 tmp[4];
#pragma unroll
      for(int i=0;i<4;i++){
        int s=tid+i*512, kt=s>>8, r=(s>>3)&31, gc=s&7;
        tmp[i]=*(const u32x4*)(hbase + (size_t)(bm+r)*(SP1*H_) + kt*64 + gc*8);
      }
#pragma unroll
      for(int i=0;i<4;i++){
        int s=tid+i*512, kt=s>>8, r=(s>>3)&31, gc=s&7, lc=gc^(r&7);
        *(u32x4*)(As + kt*2048 + r*64 + lc*8)=tmp[i];
      }
    }
    __syncthreads();
    u32x4 tmp2[4];
#pragma unroll
    for(int i=0;i<4;i++){
      int s=tid+(i+4)*512, kt=s>>8, r=(s>>3)&31, gc=s&7;
      tmp2[i]=*(const u32x4*)(hbase + (size_t)(bm+r)*(SP1*H_) + kt*64 + gc*8);
    }
    f32x4 acc0=(f32x4)(0.f), acc1=(f32x4)(0.f);
#pragma unroll
    for(int t=0;t<16;t++){
      int kt=t>>1, kk=t&1;
      f16x8 af0=frag_ld(As+kt*2048, 0,  kk*4, lane);
      f16x8 af1=frag_ld(As+kt*2048, 16, kk*4, lane);
      acc0=__builtin_amdgcn_mfma_f32_16x16x32_f16(af0,bw[t],acc0,0,0,0);
      acc1=__builtin_amdgcn_mfma_f32_16x16x32_f16(af1,bw[t],acc1,0,0,0);
    }
#pragma unroll
    for(int i=0;i<4;i++){
      int s=tid+(i+4)*512, kt=s>>8, r=(s>>3)&31, gc=s&7, lc=gc^(r&7);
      *(u32x4*)(As + kt*2048 + r*64 + lc*8)=tmp2[i];
    }
    __syncthreads();
#pragma unroll
    for(int t=16;t<32;t++){
      int kt=t>>1, kk=t&1;
      f16x8 af0=frag_ld(As+kt*2048, 0,  kk*4, lane);
      f16x8 af1=frag_ld(As+kt*2048, 16, kk*4, lane);
      acc0=__builtin_amdgcn_mfma_f32_16x16x32_f16(af0,bw[t],acc0,0,0,0);
      acc1=__builtin_amdgcn_mfma_f32_16x16x32_f16(af1,bw[t],acc1,0,0,0);
    }
#pragma unroll
    for(int r=0;r<4;r++){
      gs[(   (lane>>4)*4+r)*132 + w*16+(lane&15)]=acc0[r];
      gs[(16+(lane>>4)*4+r)*132 + w*16+(lane&15)]=acc1[r];
    }
    __syncthreads();
    {
      float4 gv=*(const float4*)&gs[rl0*132+u0*4];
      float ii=1.f/(1.f+__expf(-(gv.x+(float)xv0[0])));
      float ff=1.f/(1.f+__expf(-(gv.y+(float)xv0[1])));
      float gg=1.f-2.f/(__expf(2.f*(gv.z+(float)xv0[2]))+1.f);
      float oo=1.f/(1.f+__expf(-(gv.w+(float)xv0[3])));
      c0=ff*c0+ii*gg;
      float th=1.f-2.f/(__expf(2.f*c0)+1.f);
      store_c2(hh + ((size_t)(bm+rl0)*SP1 + tbase+dt+1)*H_ + gu, f2h(oo*th));
    }
    {
      float4 gv=*(const float4*)&gs[rl1*132+u0*4];
      float ii=1.f/(1.f+__expf(-(gv.x+(float)xv1[0])));
      float ff=1.f/(1.f+__expf(-(gv.y+(float)xv1[1])));
      float gg=1.f-2.f/(__expf(2.f*(gv.z+(float)xv1[2]))+1.f);
      float oo=1.f/(1.f+__expf(-(gv.w+(float)xv1[3])));
      c1=ff*c1+ii*gg;
      float th=1.f-2.f/(__expf(2.f*c1)+1.f);
      store_c2(hh + ((size_t)(bm+rl1)*SP1 + tbase+dt+1)*H_ + gu, f2h(oo*th));
    }
  }
  cst[(size_t)(bm+rl0)*H_+gu]=c0;
  cst[(size_t)(bm+rl1)*H_+gu]=c1;
}

// ---- fallback per-step LSTM (low-ws tier)
__global__ __launch_bounds__(256,2) void lstm_step(u16* __restrict__ hh, int slotAbs, int dt,
        const void* __restrict__ Whh, const u16* __restrict__ xg,
        float* __restrict__ cst, const int* __restrict__ flag){
  int m=*flag;
  __shared__ u16 As[64*64];
  __shared__ u16 Bs[64*64];
  __shared__ float gs[64*64];
  int tid=threadIdx.x, lane=tid&63, w=tid>>6;
  int bm=blockIdx.y*64, bn=blockIdx.x*64;
  int wm=(w&1)*32, wn=(w>>1)*32;
  f32x4 acc[2][2];
#pragma unroll
  for(int i=0;i<2;i++)
#pragma unroll
    for(int j=0;j<2;j++) acc[i][j]=(f32x4)(0.f);
  for(int k0=0;k0<H_;k0+=64){
    stage<64,0>(hh + (size_t)slotAbs*H_, 2, SP1*H_, k0, bm, 0, As, tid);
    stage<64,1>(Whh,                     m, H_,     k0, bn, 0, Bs, tid);
    __syncthreads();
#pragma unroll
    for(int kk=0;kk<2;kk++){
      f16x8 af[2], bq[2];
#pragma unroll
      for(int i=0;i<2;i++) af[i]=frag_ld(As, wm+i*16, kk*4, lane);
#pragma unroll
      for(int j=0;j<2;j++) bq[j]=frag_ld(Bs, wn+j*16, kk*4, lane);
#pragma unroll
      for(int i=0;i<2;i++)
#pragma unroll
        for(int j=0;j<2;j++)
          acc[i][j]=__builtin_amdgcn_mfma_f32_16x16x32_f16(af[i],bq[j],acc[i][j],0,0,0);
    }
    __syncthreads();
  }
  int rl=lane>>4, cl=lane&15;
#pragma unroll
  for(int j=0;j<2;j++){
    int coll=wn+j*16+cl;
#pragma unroll
    for(int i=0;i<2;i++){
#pragma unroll
      for(int r=0;r<4;r++){
        int rowl=wm+i*16+rl*4+r;
        float xv=(float)((const _Float16*)xg)[((size_t)(bm+rowl)*CH_+dt)*G_ + bn+coll];
        gs[rowl*64+coll]=acc[i][j][r] + xv;
      }
    }
  }
  __syncthreads();
#pragma unroll
  for(int p=0;p<4;p++){
    int idx=p*256+tid;
    int rowl=idx>>4, u=idx&15;
    float4 gv = *(const float4*)&gs[rowl*64+u*4];
    float ii=1.f/(1.f+__expf(-gv.x));
    float ff=1.f/(1.f+__expf(-gv.y));
    float gg=1.f-2.f/(__expf(2.f*gv.z)+1.f);
    float oo=1.f/(1.f+__expf(-gv.w));
    int gb=bm+rowl;
    int gu=(bn>>2)+u;
    size_t ci=(size_t)gb*H_+gu;
    float cn=ff*cst[ci]+ii*gg;
    cst[ci]=cn;
    float th=1.f-2.f/(__expf(2.f*cn)+1.f);
    hh[((size_t)gb*SP1 + slotAbs+1)*H_ + gu]=f2h(oo*th);
  }
}

// ---- heads as MFMA GEMM + fused log-softmax (r15-verified).
__global__ __launch_bounds__(512,1) void heads_gemm(const u16* __restrict__ hh,
      const u16* __restrict__ WH, const float* __restrict__ blf,
      const int* __restrict__ acts, void* __restrict__ out, const int* __restrict__ flag){
  int m=*flag;
  __shared__ u16 Bs[16*2048];
  __shared__ u16 As[128*64];
  __shared__ float gs[128*36];
  int tid=threadIdx.x, lane=tid&63, w=tid>>6;
  int bm=blockIdx.x*128;
#pragma unroll
  for(int i=0;i<8;i++){
    int s=tid+i*512;
    int kt=s>>8, r=(s>>3)&31, gc=s&7, lc=gc^(r&7);
    *(f16x8*)(Bs+kt*2048+r*64+lc*8) = *(const f16x8*)(WH + (size_t)r*H_ + kt*64 + gc*8);
  }
  f32x4 acc0=(f32x4)(0.f), acc1=(f32x4)(0.f);
  for(int kt=0;kt<16;kt++){
#pragma unroll
    for(int i=0;i<2;i++){
      int s0=i*512+(w<<6), s=s0+lane;
      int r=s>>3, gc=(s&7)^(r&7);
      int rg=bm+r;
      const u16* src=hh + ((size_t)(rg>>7)*SP1 + (rg&127)+1)*H_ + kt*64 + gc*8;
      u16* dst=As + s0*8;
      __builtin_amdgcn_global_load_lds((const __attribute__((address_space(1))) unsigned int*)src,
                                       (__attribute__((address_space(3))) unsigned int*)dst,
                                       16, 0, 0);
    }
    __syncthreads();
#pragma unroll
    for(int kk=0;kk<2;kk++){
      f16x8 af=frag_ld(As, w*16, kk*4, lane);
      f16x8 b0=frag_ld(Bs+kt*2048, 0,  kk*4, lane);
      f16x8 b1=frag_ld(Bs+kt*2048, 16, kk*4, lane);
      acc0=__builtin_amdgcn_mfma_f32_16x16x32_f16(af,b0,acc0,0,0,0);
      acc1=__builtin_amdgcn_mfma_f32_16x16x32_f16(af,b1,acc1,0,0,0);
    }
    __syncthreads();
  }
#pragma unroll
  for(int r=0;r<4;r++){
    gs[(w*16+(lane>>4)*4+r)*36 + (lane&15)]      = acc0[r];
    gs[(w*16+(lane>>4)*4+r)*36 + 16 + (lane&15)] = acc1[r];
  }
  __syncthreads();
  if(tid<128){
    int rg=bm+tid;
    float lg[18];
#pragma unroll
    for(int j=0;j<18;j++) lg[j]=gs[tid*36+j]+blf[j];
    float value=gs[tid*36+18]+blf[18];
    float mx=lg[0];
#pragma unroll
    for(int j=1;j<18;j++) mx=fmaxf(mx,lg[j]);
    float se=0.f, s1=0.f;
#pragma unroll
    for(int j=0;j<18;j++){ float e=__expf(lg[j]-mx); se+=e; s1+=e*(lg[j]-mx); }
    float lse=__logf(se);
    int a=acts[rg];
    float la=0.f;
#pragma unroll
    for(int j=0;j<18;j++) la = (j==a) ? lg[j] : la;
    float lp=la-mx-lse;
    float ent=lse - s1/se;
    if(m){
      ((float*)out)[rg]=lp; ((float*)out)[M_+rg]=ent; ((float*)out)[2*M_+rg]=value;
    } else {
      ((u16*)out)[rg]=f2bf(lp); ((u16*)out)[M_+rg]=f2bf(ent); ((u16*)out)[2*M_+rg]=f2bf(value);
    }
  }
}

// ---- fallback heads (no-WH tier)
__global__ __launch_bounds__(256,2) void heads_full(const u16* __restrict__ hh,
      const void* __restrict__ Wl, const void* __restrict__ Wv,
      const float* __restrict__ blf, const int* __restrict__ acts,
      void* __restrict__ out, const int* __restrict__ flag){
  int m=*flag;
  int rg = blockIdx.x*4 + (threadIdx.x>>6);
  int lane = threadIdx.x & 63;
  int b=rg>>7, t=rg&(S_-1);
  const u16* h = hh + ((size_t)b*SP1 + t+1)*H_;
  f16x8 h0=*(const f16x8*)(h + lane*16), h1=*(const f16x8*)(h + lane*16 + 8);
  float hv[16];
#pragma unroll
  for(int k=0;k<8;k++){ hv[k]=(float)h0[k]; hv[8+k]=(float)h1[k]; }
  float dots[19];
#pragma unroll
  for(int j=0;j<19;j++){
    const void* wrow = (j<18) ? Wl : Wv;
    size_t roff = (j<18) ? (size_t)j*H_ : 0;
    float wv_[16];
    if(m){
      const float* f=(const float*)wrow + roff + lane*16;
      float4 a=*(const float4*)f, b2=*(const float4*)(f+4), c=*(const float4*)(f+8), d=*(const float4*)(f+12);
      wv_[0]=a.x;wv_[1]=a.y;wv_[2]=a.z;wv_[3]=a.w; wv_[4]=b2.x;wv_[5]=b2.y;wv_[6]=b2.z;wv_[7]=b2.w;
      wv_[8]=c.x;wv_[9]=c.y;wv_[10]=c.z;wv_[11]=c.w; wv_[12]=d.x;wv_[13]=d.y;wv_[14]=d.z;wv_[15]=d.w;
    } else {
      const u16* ub=(const u16*)wrow + roff + lane*16;
      s16x8 w0=*(const s16x8*)ub, w1=*(const s16x8*)(ub+8);
#pragma unroll
      for(int k=0;k<8;k++){ wv_[k]=bf2f((u16)w0[k]); wv_[8+k]=bf2f((u16)w1[k]); }
    }
    float d=0.f;
#pragma unroll
    for(int k=0;k<16;k++) d += hv[k]*wv_[k];
#pragma unroll
    for(int mm=1;mm<64;mm<<=1) d += __shfl_xor(d, mm, 64);
    dots[j]=d;
  }
  float lg[18];
#pragma unroll
  for(int j=0;j<18;j++) lg[j]=dots[j]+blf[j];
  float value=dots[18]+blf[18];
  float mx=lg[0];
#pragma unroll
  for(int j=1;j<18;j++) mx=fmaxf(mx,lg[j]);
  float se=0.f, s1=0.f;
#pragma unroll
  for(int j=0;j<18;j++){ float e=__expf(lg[j]-mx); se+=e; s1+=e*(lg[j]-mx); }
  float lse=__logf(se);
  int a=acts[rg];
  float la=0.f;
#pragma unroll
  for(int j=0;j<18;j++) la = (j==a) ? lg[j] : la;
  float lp=la-mx-lse;
  float ent=lse - s1/se;
  if(lane==0){
    if(m){
      ((float*)out)[rg]=lp; ((float*)out)[M_+rg]=ent; ((float*)out)[2*M_+rg]=value;
    } else {
      ((u16*)out)[rg]=f2bf(lp); ((u16*)out)[M_+rg]=f2bf(ent); ((u16*)out)[2*M_+rg]=f2bf(value);
    }
  }
}

// ---- dtype detect
__global__ void detect(const u16* __restrict__ obs_w, int* __restrict__ flag){
  __shared__ float red[256];
  float mx=0.f;
  for(int i=threadIdx.x;i<4096;i+=256) mx=fmaxf(mx,fabsf(bf2f(obs_w[i])));
  red[threadIdx.x]=mx; __syncthreads();
  for(int s=128;s>0;s>>=1){
    if(threadIdx.x<s) red[threadIdx.x]=fmaxf(red[threadIdx.x],red[threadIdx.x+s]);
    __syncthreads();
  }
  if(threadIdx.x==0) *flag=(red[0]>1e4f)?1:0;
}

// ---- prep
__global__ void prep(const void* bih, const void* bhh, const void* b1, const void* bl, const void* bv,
                     const void* cx, const void* hx,
                     float* biasg, float* b1f, float* blf, float* cst, u16* hh,
                     int* cnt, const int* __restrict__ flag){
  int m=*flag;
  size_t i=(size_t)blockIdx.x*256+threadIdx.x;
  if(i<G_){ size_t rm=(i&3)*H_+(i>>2); biasg[i]=ldf(bih,rm,m)+ldf(bhh,rm,m); return; }
  i-=G_;
  if(i<H_){ b1f[i]=ldf(b1,i,m); return; }
  i-=H_;
  if(i<19){ blf[i]=(i<18)?ldf(bl,i,m):ldf(bv,0,m); return; }
  i-=19;
  if(i<512){ cnt[i]=0; return; }
  i-=512;
  if(i<(size_t)B_*H_){ cst[i]=ldf(cx,i,m); return; }
  i-=(size_t)B_*H_;
  if(i<(size_t)B_*H_){
    size_t b=i>>10, k=i&1023;
    hh[b*(SP1*H_) + k]=f2h(ldf(hx,i,m));   // seed at slot 0
  }
}

// ---- weight pre-conversion
__global__ void convw(const void* W1, const void* Wih, const void* Whh,
                      const void* Wl, const void* Wv,
                      u16* W1h, u16* Wihp, u16* Whhp, u16* WH,
                      const int* __restrict__ flag){
  int m=*flag;
  size_t i=((size_t)blockIdx.x*256+threadIdx.x)*8;
  const size_t n1=(size_t)H_*F_, n2=(size_t)G_*H_, n3=(size_t)32*H_;
  if(i<n1){ *(f16x8*)(W1h+i)=load8_h(W1,i,m); return; }
  i-=n1;
  if(i<n2){ size_t p=i>>10, c=i&1023; size_t sr=(p&3)*H_+(p>>2);
            *(f16x8*)(Wihp+i)=load8_h(Wih, sr*H_+c, m); return; }
  i-=n2;
  if(i<n2){ size_t p=i>>10, c=i&1023; size_t sr=(p&3)*H_+(p>>2);
            *(f16x8*)(Whhp+i)=load8_h(Whh, sr*H_+c, m); return; }
  i-=n2;
  if(i<n3){
    size_t j=i>>10, c=i&1023;
    f16x8 v;
    if(j<18)      v=load8_h(Wl, j*H_+c, m);
    else if(j==18) v=load8_h(Wv, c, m);
    else{ for(int k=0;k<8;k++) v[k]=(_Float16)0.f; }
    *(f16x8*)(WH+i)=v;
  }
}
__global__ void convobs(const void* obs, u16* obsh, const int* __restrict__ flag){
  int m=*flag;
  size_t i=((size_t)blockIdx.x*256+threadIdx.x)*8;
  if(i<(size_t)M_*F_) *(f16x8*)(obsh+i)=load8_h(obs,i,m);
}

extern "C" void kernel_launch(void* const* d_in, const int* in_sizes, int n_in,
                              void* d_out, int out_size, void* d_ws, size_t ws_size,
                              hipStream_t stream){
  const void* obs=d_in[0];
  const void* hx =d_in[1];
  const void* cx =d_in[2];
  const int* acts=(const int*)d_in[3];
  const void* W1 =d_in[4];
  const void* b1 =d_in[5];
  const void* Wih=d_in[6];
  const void* bih=d_in[7];
  const void* Whh=d_in[8];
  const void* bhh=d_in[9];
  const void* Wv =d_in[10];
  const void* bv =d_in[11];
  const void* Wl =d_in[12];
  const void* bl =d_in[13];

  char* w=(char*)d_ws;
  auto alloc=[&](size_t n){ char* p=w; w+=((n+255)&~(size_t)255); return p; };
  int*   flag =(int*)alloc(4);
  int*   cnt  =(int*)alloc(512*4);
  float* biasg=(float*)alloc((size_t)G_*4);
  float* b1f  =(float*)alloc((size_t)H_*4);
  float* blf  =(float*)alloc(32*4);
  float* cst  =(float*)alloc((size_t)B_*H_*4);
  u16*   hh   =(u16*)alloc((size_t)B_*SP1*H_*2);   // 67.6 MB
  u16*   xc   =(u16*)alloc((size_t)CR_*H_*2);      // 16.8 MB
  u16*   xg   =(u16*)alloc((size_t)CR_*G_*2);      // 67 MB fp16 xg chunk (CH_=32)
  // tiers
  size_t nW=((size_t)H_*F_ + 2*(size_t)G_*H_ + 32*(size_t)H_)*2 + 1024;
  bool pathW = ((size_t)(w-(char*)d_ws) + nW) <= ws_size;
  u16 *W1h=0,*Wihp=0,*Whhp=0,*WH=0;
  if(pathW){ W1h=(u16*)alloc((size_t)H_*F_*2); Wihp=(u16*)alloc((size_t)G_*H_*2);
             Whhp=(u16*)alloc((size_t)G_*H_*2); WH=(u16*)alloc((size_t)32*H_*2); }
  size_t nXC=(size_t)M_*H_*2 + 256;
  bool pathXC = pathW && (((size_t)(w-(char*)d_ws) + nXC) <= ws_size);
  u16* xcf=0; if(pathXC) xcf=(u16*)alloc((size_t)M_*H_*2);
  size_t nO=(size_t)M_*F_*2 + 256;
  bool pathO = pathXC && (((size_t)(w-(char*)d_ws) + nO) <= ws_size);
  u16* obsh=0; if(pathO) obsh=(u16*)alloc((size_t)M_*F_*2);

  detect<<<1,256,0,stream>>>((const u16*)obs, flag);
  {
    int total=G_+H_+19+512+B_*H_+B_*H_;
    prep<<<(total+255)/256,256,0,stream>>>(bih,bhh,b1,bl,bv,cx,hx, biasg,b1f,blf,cst,hh,cnt, flag);
  }
  if(pathW){
    size_t n=((size_t)H_*F_+2*(size_t)G_*H_+32*(size_t)H_)/8;
    convw<<<(int)((n+255)/256),256,0,stream>>>(W1,Wih,Whh,Wl,Wv, W1h,Wihp,Whhp,WH, flag);
  }
  if(pathO){
    size_t n=(size_t)M_*F_/8;
    convobs<<<(int)((n+255)/256),256,0,stream>>>(obs, obsh, flag);
  }
  if(pathXC){
    gemm128<0,0,0><<<dim3(H_/128, M_/128),256,0,stream>>>(
        pathO?(const void*)obsh:obs, pathW?(const void*)W1h:W1, xcf, b1f, flag,
        F_, F_, F_, H_, 0, pathO?2:-1, pathW?2:-1);
  }

  const int NC=S_/CH_;
  for(int c=0;c<NC;c++){
    int t0=c*CH_;
    if(!pathXC){
      gemm128<2,0,0><<<dim3(H_/128, CR_/128),256,0,stream>>>(
          obs, pathW?(const void*)W1h:W1, xc, b1f, flag, F_, F_, F_, H_, t0, -1, pathW?2:-1);
    }
    if(pathXC)
      gemm128<2,0,2><<<dim3(G_/128, CR_/128),256,0,stream>>>(
          xcf, Wihp, xg, biasg, flag, H_, H_, H_, G_, t0, 2, 2);
    else if(pathW)
      gemm128<0,0,2><<<dim3(G_/128, CR_/128),256,0,stream>>>(
          xc, Wihp, xg, biasg, flag, H_, H_, H_, G_, 0, 2, 2);
    else
      gemm128<0,1,2><<<dim3(G_/128, CR_/128),256,0,stream>>>(
          xc, Wih, xg, biasg, flag, H_, H_, H_, G_, 0, 2, -1);

    if(pathW)
      lstm_persist<<<256,512,0,stream>>>(hh, Whhp, xg, cst, cnt, t0);
    else
      for(int dt=0;dt<CH_;dt++)
        lstm_step<<<dim3(G_/64, B_/64),256,0,stream>>>(hh, t0+dt, dt, Whh, xg, cst, flag);
  }

  if(pathW)
    heads_gemm<<<dim3(M_/128),512,0,stream>>>(hh, WH, blf, acts, d_out, flag);
  else
    heads_full<<<dim3(M_/4),256,0,stream>>>(hh, Wl, Wv, blf, acts, d_out, flag);
}

// Round 20
// 1025.427 us; speedup vs baseline: 1.2643x; 1.0039x over previous
//
#include <hip/hip_runtime.h>

#define B_ 256
#define S_ 128
#define SP1 (S_+1)
#define F_ 512
#define H_ 1024
#define A_ 18
#define M_ (B_*S_)      // 32768 output rows (b*S+s)
#define G_ (4*H_)       // 4096 gate cols, permuted unit-major: p = unit*4 + {i,f,g,o}
#define CH_ 32          // timesteps per chunk (4 chunks)
#define CR_ (B_*CH_)    // 8192 rows per chunk

typedef unsigned short u16;
typedef __attribute__((ext_vector_type(8))) _Float16 f16x8;  // 8 fp16 = 4 VGPR
typedef __attribute__((ext_vector_type(4))) _Float16 f16x4;
typedef __attribute__((ext_vector_type(8))) short   s16x8;
typedef __attribute__((ext_vector_type(4))) float f32x4;
typedef __attribute__((ext_vector_type(4))) unsigned int u32x4;

__device__ __forceinline__ float bf2f(u16 u){
  union{unsigned int i; float f;} v; v.i=((unsigned int)u)<<16; return v.f;
}
__device__ __forceinline__ u16 f2bf(float f){
  unsigned int i=__float_as_uint(f);
  unsigned int r=(i+0x7fffu+((i>>16)&1u))>>16;   // RNE
  return (u16)r;
}
__device__ __forceinline__ u16 f2h(float f){
  _Float16 h=(_Float16)f;
  union{_Float16 h; u16 u;} v; v.h=h; return v.u;
}
__device__ __forceinline__ float ldf(const void* p, size_t i, int m){
  return m ? ((const float*)p)[i] : bf2f(((const u16*)p)[i]);
}
// load 8 logical floats -> fp16x8. mode 0: bf16 src, 1: fp32 src, 2: raw fp16 src.
__device__ __forceinline__ f16x8 load8_h(const void* base, size_t off, int m){
  f16x8 v;
  if(m==2) return *(const f16x8*)((const u16*)base + off);
  if(m==1){
    const float* f=(const float*)base + off;
    float4 a=*(const float4*)f; float4 b=*(const float4*)(f+4);
    v[0]=(_Float16)a.x; v[1]=(_Float16)a.y; v[2]=(_Float16)a.z; v[3]=(_Float16)a.w;
    v[4]=(_Float16)b.x; v[5]=(_Float16)b.y; v[6]=(_Float16)b.z; v[7]=(_Float16)b.w;
    return v;
  }
  s16x8 w=*(const s16x8*)((const u16*)base + off);
#pragma unroll
  for(int k=0;k<8;k++) v[k]=(_Float16)bf2f((u16)w[k]);
  return v;
}

// ---- coherent (cross-XCD, LLC-routed) accesses: bypass L1+L2 via sc0 sc1.
__device__ __forceinline__ void store_c2(u16* p, u16 v){
  unsigned int vv=v;
  asm volatile("global_store_short %0, %1, off sc0 sc1" :: "v"(p), "v"(vv) : "memory");
}
__device__ __forceinline__ int load_c4(const int* p){
  int r;
  asm volatile("global_load_dword %0, %1, off sc0 sc1" : "=v"(r) : "v"(p));
  return r;
}
__device__ __forceinline__ void store_c4(int* p, int v){
  asm volatile("global_store_dword %0, %1, off sc0 sc1" :: "v"(p), "v"(v) : "memory");
}

// ---- store-flag group barrier (32 blocks)
__device__ __forceinline__ void bar_flags32(int* flags, int target, int gi, int lane, int w){
  asm volatile("s_waitcnt vmcnt(0)" ::: "memory");   // own h stores at LLC
  __syncthreads();
  if(w==0){
    if(lane==0) store_c4(flags+gi, target);
    while(true){
      int v=load_c4(flags+(lane&31));
      asm volatile("s_waitcnt vmcnt(0)" ::: "memory");
      if(__all(v>=target)) break;
      __builtin_amdgcn_s_sleep(1);
    }
  }
  __syncthreads();
}

// ---- Stage ROWS x 64 fp16 tile into LDS [ROWS][64], XOR-swizzled (256-thr blocks).
// MAP 0: row=rowoff+r. MAP 1: gate-permute. MAP 2: x rows for chunk (rg=b*CH_+dt).
template<int ROWS, int MAP>
__device__ __forceinline__ void stage(const void* base, int mode, int lda, int k0,
                                      int rowoff, int t0, u16* lds, int tid){
  if(mode==2){
    constexpr int NI=(ROWS*8)/256;
    int wv=tid>>6, l=tid&63;
#pragma unroll
    for(int i=0;i<NI;i++){
      int s0=i*256+(wv<<6), s=s0+l;
      int r=s>>3, gc=(s&7)^(r&7);
      int p=rowoff+r, sr;
      if(MAP==0)      sr=p;
      else if(MAP==1) sr=(p&3)*H_+(p>>2);
      else            sr=(p/CH_)*S_+t0+(p%CH_);
      const u16* src=(const u16*)base + (size_t)sr*lda + k0 + gc*8;
      u16* dst=lds + s0*8;             // wave-uniform; HW adds lane*16B
      __builtin_amdgcn_global_load_lds((const __attribute__((address_space(1))) unsigned int*)src,
                                       (__attribute__((address_space(3))) unsigned int*)dst,
                                       16, 0, 0);
    }
  } else {
#pragma unroll
    for(int s0=tid; s0<ROWS*8; s0+=256){
      int r=s0>>3, gc=s0&7, lc=gc^(r&7);
      int p=rowoff+r, sr;
      if(MAP==0)      sr=p;
      else if(MAP==1) sr=(p&3)*H_+(p>>2);
      else            sr=(p/CH_)*S_+t0+(p%CH_);
      f16x8 v=load8_h(base, (size_t)sr*lda + k0 + gc*8, mode);
      *(f16x8*)(lds + r*64 + lc*8)=v;
    }
  }
}

// MFMA 16x16x32 fragment from swizzled LDS tile [*][64].
__device__ __forceinline__ f16x8 frag_ld(const u16* lds, int r0, int kc, int lane){
  int r = r0 + (lane&15);
  int c = (kc + (lane>>4)) ^ (r&7);
  return *(const f16x8*)(lds + r*64 + c*8);
}

// ---- 128x128-tile GEMM. OUTMODE 0: relu+fp16. 1: fp32. 2: fp16.
template<int AMAP, int BMAP, int OUTMODE>
__global__ __launch_bounds__(256,3) void gemm128(const void* A, const void* Bt, void* C,
    const float* __restrict__ biasf, const int* __restrict__ flag,
    int K, int lda, int ldb, int ldc, int t0, int amode, int bmode){
  int m=*flag;
  int am = amode<0 ? m : amode;
  int bm_ = bmode<0 ? m : bmode;
  __shared__ u16 As[128*64];
  __shared__ u16 Bs[128*64];
  int tid=threadIdx.x, lane=tid&63, w=tid>>6;
  int bm=blockIdx.y*128, bn=blockIdx.x*128;
  int wm=(w&1)*64, wn=(w>>1)*64;
  f32x4 acc[4][4];
#pragma unroll
  for(int i=0;i<4;i++)
#pragma unroll
    for(int j=0;j<4;j++) acc[i][j]=(f32x4)(0.f);
  for(int k0=0;k0<K;k0+=64){
    stage<128,AMAP>(A , am,  lda, k0, bm, t0, As, tid);
    stage<128,BMAP>(Bt, bm_, ldb, k0, bn, t0, Bs, tid);
    __syncthreads();
#pragma unroll
    for(int kk=0;kk<2;kk++){
      f16x8 af[4], bq[4];
#pragma unroll
      for(int i=0;i<4;i++) af[i]=frag_ld(As, wm+i*16, kk*4, lane);
#pragma unroll
      for(int j=0;j<4;j++) bq[j]=frag_ld(Bs, wn+j*16, kk*4, lane);
#pragma unroll
      for(int i=0;i<4;i++)
#pragma unroll
        for(int j=0;j<4;j++)
          acc[i][j]=__builtin_amdgcn_mfma_f32_16x16x32_f16(af[i],bq[j],acc[i][j],0,0,0);
    }
    __syncthreads();
  }
  int rl=lane>>4, cl=lane&15;
#pragma unroll
  for(int j=0;j<4;j++){
    int col=bn+wn+j*16+cl;
    float bb=biasf[col];
#pragma unroll
    for(int i=0;i<4;i++){
#pragma unroll
      for(int r=0;r<4;r++){
        int row=bm+wm+i*16+rl*4+r;
        float v=acc[i][j][r]+bb;
        if(OUTMODE==0){ v=fmaxf(v,0.f); ((u16*)C)[(size_t)row*ldc+col]=f2h(v); }
        else if(OUTMODE==2){ ((u16*)C)[(size_t)row*ldc+col]=f2h(v); }
        else { ((float*)C)[(size_t)row*ldc+col]=v; }
      }
    }
  }
}

// ---- persistent chunk-LSTM (r19-verified; elementwise re-mapped: thread owns TWO
// ADJACENT units of one row -> packed 4-byte coherent h store, float2 c-state).
__global__ __launch_bounds__(512,2) void lstm_persist(u16* __restrict__ hh,
        const u16* __restrict__ Whhp, const u16* __restrict__ xgp,
        float* __restrict__ cst, int* __restrict__ cntc, int tbase){
  __shared__ u16 As[16*2048];     // 64 KB: 16 k-tiles [32][64], XOR-swizzled
  __shared__ float gs[32*132];    // 16.9 KB, stride 132
  int tid=threadIdx.x, lane=tid&63, w=tid>>6;
  int grp=blockIdx.x&7, ci=blockIdx.x>>3;
  int bm=grp*32, bn=ci*128;
  int* flags = cntc + grp*64;

  f16x8 bw[32];
#pragma unroll
  for(int t=0;t<32;t++){
    int p = bn + w*16 + (lane&15);
    int k = t*32 + (lane>>4)*8;
    bw[t]=*(const f16x8*)(Whhp + (size_t)p*H_ + k);
  }
#pragma unroll
  for(int t=0;t<32;t++) asm volatile("" : "+a"(bw[t]));

  // elementwise ownership: row=tid>>4 (0..31), units up, up+1 (up=(tid&15)*2)
  int row=tid>>4, up=(tid&15)*2;
  int gu=(bn>>2)+up;                               // even -> 4B/8B/16B alignment holds
  float2 cp=*(const float2*)&cst[(size_t)(bm+row)*H_+gu];

  for(int dt=0;dt<CH_;dt++){
    if(dt) bar_flags32(flags, tbase+dt, ci, lane, w);
    // xg prefetch (both units, one 16B load): overlaps stage+MFMA
    f16x8 xv=*(const f16x8*)(xgp + ((size_t)(bm+row)*CH_+dt)*G_ + bn + up*4);
    const u16* hbase = hh + (size_t)(tbase+dt)*H_;   // read slot tbase+dt
    {
      u32x4 tmp[4];
#pragma unroll
      for(int i=0;i<4;i++){
        int s=tid+i*512, kt=s>>8, r=(s>>3)&31, gc=s&7;
        tmp[i]=*(const u32x4*)(hbase + (size_t)(bm+r)*(SP1*H_) + kt*64 + gc*8);
      }
#pragma unroll
      for(int i=0;i<4;i++){
        int s=tid+i*512, kt=s>>8, r=(s>>3)&31, gc=s&7, lc=gc^(r&7);
        *(u32x4*)(As + kt*2048 + r*64 + lc*8)=tmp[i];
      }
    }
    __syncthreads();
    u32x4 tmp2[4];
#pragma unroll
    for(int i=0;i<4;i++){
      int s=tid+(i+4)*512, kt=s>>8, r=(s>>3)&31, gc=s&7;
      tmp2[i]=*(const u32x4*)(hbase + (size_t)(bm+r)*(SP1*H_) + kt*64 + gc*8);
    }
    f32x4 acc0=(f32x4)(0.f), acc1=(f32x4)(0.f);
#pragma unroll
    for(int t=0;t<16;t++){
      int kt=t>>1, kk=t&1;
      f16x8 af0=frag_ld(As+kt*2048, 0,  kk*4, lane);
      f16x8 af1=frag_ld(As+kt*2048, 16, kk*4, lane);
      acc0=__builtin_amdgcn_mfma_f32_16x16x32_f16(af0,bw[t],acc0,0,0,0);
      acc1=__builtin_amdgcn_mfma_f32_16x16x32_f16(af1,bw[t],acc1,0,0,0);
    }
#pragma unroll
    for(int i=0;i<4;i++){
      int s=tid+(i+4)*512, kt=s>>8, r=(s>>3)&31, gc=s&7, lc=gc^(r&7);
      *(u32x4*)(As + kt*2048 + r*64 + lc*8)=tmp2[i];
    }
    __syncthreads();
#pragma unroll
    for(int t=16;t<32;t++){
      int kt=t>>1, kk=t&1;
      f16x8 af0=frag_ld(As+kt*2048, 0,  kk*4, lane);
      f16x8 af1=frag_ld(As+kt*2048, 16, kk*4, lane);
      acc0=__builtin_amdgcn_mfma_f32_16x16x32_f16(af0,bw[t],acc0,0,0,0);
      acc1=__builtin_amdgcn_mfma_f32_16x16x32_f16(af1,bw[t],acc1,0,0,0);
    }
#pragma unroll
    for(int r=0;r<4;r++){
      gs[(   (lane>>4)*4+r)*132 + w*16+(lane&15)]=acc0[r];
      gs[(16+(lane>>4)*4+r)*132 + w*16+(lane&15)]=acc1[r];
    }
    __syncthreads();
    // elementwise: two adjacent units of one row; ONE packed 4-byte coherent store
    {
      float4 g0=*(const float4*)&gs[row*132+up*4];
      float4 g1=*(const float4*)&gs[row*132+up*4+4];
      float i0=1.f/(1.f+__expf(-(g0.x+(float)xv[0])));
      float f0=1.f/(1.f+__expf(-(g0.y+(float)xv[1])));
      float gg0=1.f-2.f/(__expf(2.f*(g0.z+(float)xv[2]))+1.f);
      float o0=1.f/(1.f+__expf(-(g0.w+(float)xv[3])));
      cp.x=f0*cp.x+i0*gg0;
      float th0=1.f-2.f/(__expf(2.f*cp.x)+1.f);
      float i1=1.f/(1.f+__expf(-(g1.x+(float)xv[4])));
      float f1=1.f/(1.f+__expf(-(g1.y+(float)xv[5])));
      float gg1=1.f-2.f/(__expf(2.f*(g1.z+(float)xv[6]))+1.f);
      float o1=1.f/(1.f+__expf(-(g1.w+(float)xv[7])));
      cp.y=f1*cp.y+i1*gg1;
      float th1=1.f-2.f/(__expf(2.f*cp.y)+1.f);
      unsigned int packed=(unsigned int)f2h(o0*th0) | ((unsigned int)f2h(o1*th1)<<16);
      store_c4((int*)(hh + ((size_t)(bm+row)*SP1 + tbase+dt+1)*H_ + gu), (int)packed);
    }
  }
  *(float2*)&cst[(size_t)(bm+row)*H_+gu]=cp;
}

// ---- fallback per-step LSTM (low-ws tier)
__global__ __launch_bounds__(256,2) void lstm_step(u16* __restrict__ hh, int slotAbs, int dt,
        const void* __restrict__ Whh, const u16* __restrict__ xg,
        float* __restrict__ cst, const int* __restrict__ flag){
  int m=*flag;
  __shared__ u16 As[64*64];
  __shared__ u16 Bs[64*64];
  __shared__ float gs[64*64];
  int tid=threadIdx.x, lane=tid&63, w=tid>>6;
  int bm=blockIdx.y*64, bn=blockIdx.x*64;
  int wm=(w&1)*32, wn=(w>>1)*32;
  f32x4 acc[2][2];
#pragma unroll
  for(int i=0;i<2;i++)
#pragma unroll
    for(int j=0;j<2;j++) acc[i][j]=(f32x4)(0.f);
  for(int k0=0;k0<H_;k0+=64){
    stage<64,0>(hh + (size_t)slotAbs*H_, 2, SP1*H_, k0, bm, 0, As, tid);
    stage<64,1>(Whh,                     m, H_,     k0, bn, 0, Bs, tid);
    __syncthreads();
#pragma unroll
    for(int kk=0;kk<2;kk++){
      f16x8 af[2], bq[2];
#pragma unroll
      for(int i=0;i<2;i++) af[i]=frag_ld(As, wm+i*16, kk*4, lane);
#pragma unroll
      for(int j=0;j<2;j++) bq[j]=frag_ld(Bs, wn+j*16, kk*4, lane);
#pragma unroll
      for(int i=0;i<2;i++)
#pragma unroll
        for(int j=0;j<2;j++)
          acc[i][j]=__builtin_amdgcn_mfma_f32_16x16x32_f16(af[i],bq[j],acc[i][j],0,0,0);
    }
    __syncthreads();
  }
  int rl=lane>>4, cl=lane&15;
#pragma unroll
  for(int j=0;j<2;j++){
    int coll=wn+j*16+cl;
#pragma unroll
    for(int i=0;i<2;i++){
#pragma unroll
      for(int r=0;r<4;r++){
        int rowl=wm+i*16+rl*4+r;
        float xv=(float)((const _Float16*)xg)[((size_t)(bm+rowl)*CH_+dt)*G_ + bn+coll];
        gs[rowl*64+coll]=acc[i][j][r] + xv;
      }
    }
  }
  __syncthreads();
#pragma unroll
  for(int p=0;p<4;p++){
    int idx=p*256+tid;
    int rowl=idx>>4, u=idx&15;
    float4 gv = *(const float4*)&gs[rowl*64+u*4];
    float ii=1.f/(1.f+__expf(-gv.x));
    float ff=1.f/(1.f+__expf(-gv.y));
    float gg=1.f-2.f/(__expf(2.f*gv.z)+1.f);
    float oo=1.f/(1.f+__expf(-gv.w));
    int gb=bm+rowl;
    int gu=(bn>>2)+u;
    size_t ci=(size_t)gb*H_+gu;
    float cn=ff*cst[ci]+ii*gg;
    cst[ci]=cn;
    float th=1.f-2.f/(__expf(2.f*cn)+1.f);
    hh[((size_t)gb*SP1 + slotAbs+1)*H_ + gu]=f2h(oo*th);
  }
}

// ---- heads as MFMA GEMM + fused log-softmax (r15-verified).
__global__ __launch_bounds__(512,1) void heads_gemm(const u16* __restrict__ hh,
      const u16* __restrict__ WH, const float* __restrict__ blf,
      const int* __restrict__ acts, void* __restrict__ out, const int* __restrict__ flag){
  int m=*flag;
  __shared__ u16 Bs[16*2048];
  __shared__ u16 As[128*64];
  __shared__ float gs[128*36];
  int tid=threadIdx.x, lane=tid&63, w=tid>>6;
  int bm=blockIdx.x*128;
#pragma unroll
  for(int i=0;i<8;i++){
    int s=tid+i*512;
    int kt=s>>8, r=(s>>3)&31, gc=s&7, lc=gc^(r&7);
    *(f16x8*)(Bs+kt*2048+r*64+lc*8) = *(const f16x8*)(WH + (size_t)r*H_ + kt*64 + gc*8);
  }
  f32x4 acc0=(f32x4)(0.f), acc1=(f32x4)(0.f);
  for(int kt=0;kt<16;kt++){
#pragma unroll
    for(int i=0;i<2;i++){
      int s0=i*512+(w<<6), s=s0+lane;
      int r=s>>3, gc=(s&7)^(r&7);
      int rg=bm+r;
      const u16* src=hh + ((size_t)(rg>>7)*SP1 + (rg&127)+1)*H_ + kt*64 + gc*8;
      u16* dst=As + s0*8;
      __builtin_amdgcn_global_load_lds((const __attribute__((address_space(1))) unsigned int*)src,
                                       (__attribute__((address_space(3))) unsigned int*)dst,
                                       16, 0, 0);
    }
    __syncthreads();
#pragma unroll
    for(int kk=0;kk<2;kk++){
      f16x8 af=frag_ld(As, w*16, kk*4, lane);
      f16x8 b0=frag_ld(Bs+kt*2048, 0,  kk*4, lane);
      f16x8 b1=frag_ld(Bs+kt*2048, 16, kk*4, lane);
      acc0=__builtin_amdgcn_mfma_f32_16x16x32_f16(af,b0,acc0,0,0,0);
      acc1=__builtin_amdgcn_mfma_f32_16x16x32_f16(af,b1,acc1,0,0,0);
    }
    __syncthreads();
  }
#pragma unroll
  for(int r=0;r<4;r++){
    gs[(w*16+(lane>>4)*4+r)*36 + (lane&15)]      = acc0[r];
    gs[(w*16+(lane>>4)*4+r)*36 + 16 + (lane&15)] = acc1[r];
  }
  __syncthreads();
  if(tid<128){
    int rg=bm+tid;
    float lg[18];
#pragma unroll
    for(int j=0;j<18;j++) lg[j]=gs[tid*36+j]+blf[j];
    float value=gs[tid*36+18]+blf[18];
    float mx=lg[0];
#pragma unroll
    for(int j=1;j<18;j++) mx=fmaxf(mx,lg[j]);
    float se=0.f, s1=0.f;
#pragma unroll
    for(int j=0;j<18;j++){ float e=__expf(lg[j]-mx); se+=e; s1+=e*(lg[j]-mx); }
    float lse=__logf(se);
    int a=acts[rg];
    float la=0.f;
#pragma unroll
    for(int j=0;j<18;j++) la = (j==a) ? lg[j] : la;
    float lp=la-mx-lse;
    float ent=lse - s1/se;
    if(m){
      ((float*)out)[rg]=lp; ((float*)out)[M_+rg]=ent; ((float*)out)[2*M_+rg]=value;
    } else {
      ((u16*)out)[rg]=f2bf(lp); ((u16*)out)[M_+rg]=f2bf(ent); ((u16*)out)[2*M_+rg]=f2bf(value);
    }
  }
}

// ---- fallback heads (no-WH tier)
__global__ __launch_bounds__(256,2) void heads_full(const u16* __restrict__ hh,
      const void* __restrict__ Wl, const void* __restrict__ Wv,
      const float* __restrict__ blf, const int* __restrict__ acts,
      void* __restrict__ out, const int* __restrict__ flag){
  int m=*flag;
  int rg = blockIdx.x*4 + (threadIdx.x>>6);
  int lane = threadIdx.x & 63;
  int b=rg>>7, t=rg&(S_-1);
  const u16* h = hh + ((size_t)b*SP1 + t+1)*H_;
  f16x8 h0=*(const f16x8*)(h + lane*16), h1=*(const f16x8*)(h + lane*16 + 8);
  float hv[16];
#pragma unroll
  for(int k=0;k<8;k++){ hv[k]=(float)h0[k]; hv[8+k]=(float)h1[k]; }
  float dots[19];
#pragma unroll
  for(int j=0;j<19;j++){
    const void* wrow = (j<18) ? Wl : Wv;
    size_t roff = (j<18) ? (size_t)j*H_ : 0;
    float wv_[16];
    if(m){
      const float* f=(const float*)wrow + roff + lane*16;
      float4 a=*(const float4*)f, b2=*(const float4*)(f+4), c=*(const float4*)(f+8), d=*(const float4*)(f+12);
      wv_[0]=a.x;wv_[1]=a.y;wv_[2]=a.z;wv_[3]=a.w; wv_[4]=b2.x;wv_[5]=b2.y;wv_[6]=b2.z;wv_[7]=b2.w;
      wv_[8]=c.x;wv_[9]=c.y;wv_[10]=c.z;wv_[11]=c.w; wv_[12]=d.x;wv_[13]=d.y;wv_[14]=d.z;wv_[15]=d.w;
    } else {
      const u16* ub=(const u16*)wrow + roff + lane*16;
      s16x8 w0=*(const s16x8*)ub, w1=*(const s16x8*)(ub+8);
#pragma unroll
      for(int k=0;k<8;k++){ wv_[k]=bf2f((u16)w0[k]); wv_[8+k]=bf2f((u16)w1[k]); }
    }
    float d=0.f;
#pragma unroll
    for(int k=0;k<16;k++) d += hv[k]*wv_[k];
#pragma unroll
    for(int mm=1;mm<64;mm<<=1) d += __shfl_xor(d, mm, 64);
    dots[j]=d;
  }
  float lg[18];
#pragma unroll
  for(int j=0;j<18;j++) lg[j]=dots[j]+blf[j];
  float value=dots[18]+blf[18];
  float mx=lg[0];
#pragma unroll
  for(int j=1;j<18;j++) mx=fmaxf(mx,lg[j]);
  float se=0.f, s1=0.f;
#pragma unroll
  for(int j=0;j<18;j++){ float e=__expf(lg[j]-mx); se+=e; s1+=e*(lg[j]-mx); }
  float lse=__logf(se);
  int a=acts[rg];
  float la=0.f;
#pragma unroll
  for(int j=0;j<18;j++) la = (j==a) ? lg[j] : la;
  float lp=la-mx-lse;
  float ent=lse - s1/se;
  if(lane==0){
    if(m){
      ((float*)out)[rg]=lp; ((float*)out)[M_+rg]=ent; ((float*)out)[2*M_+rg]=value;
    } else {
      ((u16*)out)[rg]=f2bf(lp); ((u16*)out)[M_+rg]=f2bf(ent); ((u16*)out)[2*M_+rg]=f2bf(value);
    }
  }
}

// ---- dtype detect
__global__ void detect(const u16* __restrict__ obs_w, int* __restrict__ flag){
  __shared__ float red[256];
  float mx=0.f;
  for(int i=threadIdx.x;i<4096;i+=256) mx=fmaxf(mx,fabsf(bf2f(obs_w[i])));
  red[threadIdx.x]=mx; __syncthreads();
  for(int s=128;s>0;s>>=1){
    if(threadIdx.x<s) red[threadIdx.x]=fmaxf(red[threadIdx.x],red[threadIdx.x+s]);
    __syncthreads();
  }
  if(threadIdx.x==0) *flag=(red[0]>1e4f)?1:0;
}

// ---- prep
__global__ void prep(const void* bih, const void* bhh, const void* b1, const void* bl, const void* bv,
                     const void* cx, const void* hx,
                     float* biasg, float* b1f, float* blf, float* cst, u16* hh,
                     int* cnt, const int* __restrict__ flag){
  int m=*flag;
  size_t i=(size_t)blockIdx.x*256+threadIdx.x;
  if(i<G_){ size_t rm=(i&3)*H_+(i>>2); biasg[i]=ldf(bih,rm,m)+ldf(bhh,rm,m); return; }
  i-=G_;
  if(i<H_){ b1f[i]=ldf(b1,i,m); return; }
  i-=H_;
  if(i<19){ blf[i]=(i<18)?ldf(bl,i,m):ldf(bv,0,m); return; }
  i-=19;
  if(i<512){ cnt[i]=0; return; }
  i-=512;
  if(i<(size_t)B_*H_){ cst[i]=ldf(cx,i,m); return; }
  i-=(size_t)B_*H_;
  if(i<(size_t)B_*H_){
    size_t b=i>>10, k=i&1023;
    hh[b*(SP1*H_) + k]=f2h(ldf(hx,i,m));   // seed at slot 0
  }
}

// ---- weight pre-conversion
__global__ void convw(const void* W1, const void* Wih, const void* Whh,
                      const void* Wl, const void* Wv,
                      u16* W1h, u16* Wihp, u16* Whhp, u16* WH,
                      const int* __restrict__ flag){
  int m=*flag;
  size_t i=((size_t)blockIdx.x*256+threadIdx.x)*8;
  const size_t n1=(size_t)H_*F_, n2=(size_t)G_*H_, n3=(size_t)32*H_;
  if(i<n1){ *(f16x8*)(W1h+i)=load8_h(W1,i,m); return; }
  i-=n1;
  if(i<n2){ size_t p=i>>10, c=i&1023; size_t sr=(p&3)*H_+(p>>2);
            *(f16x8*)(Wihp+i)=load8_h(Wih, sr*H_+c, m); return; }
  i-=n2;
  if(i<n2){ size_t p=i>>10, c=i&1023; size_t sr=(p&3)*H_+(p>>2);
            *(f16x8*)(Whhp+i)=load8_h(Whh, sr*H_+c, m); return; }
  i-=n2;
  if(i<n3){
    size_t j=i>>10, c=i&1023;
    f16x8 v;
    if(j<18)      v=load8_h(Wl, j*H_+c, m);
    else if(j==18) v=load8_h(Wv, c, m);
    else{ for(int k=0;k<8;k++) v[k]=(_Float16)0.f; }
    *(f16x8*)(WH+i)=v;
  }
}
__global__ void convobs(const void* obs, u16* obsh, const int* __restrict__ flag){
  int m=*flag;
  size_t i=((size_t)blockIdx.x*256+threadIdx.x)*8;
  if(i<(size_t)M_*F_) *(f16x8*)(obsh+i)=load8_h(obs,i,m);
}

extern "C" void kernel_launch(void* const* d_in, const int* in_sizes, int n_in,
                              void* d_out, int out_size, void* d_ws, size_t ws_size,
                              hipStream_t stream){
  const void* obs=d_in[0];
  const void* hx =d_in[1];
  const void* cx =d_in[2];
  const int* acts=(const int*)d_in[3];
  const void* W1 =d_in[4];
  const void* b1 =d_in[5];
  const void* Wih=d_in[6];
  const void* bih=d_in[7];
  const void* Whh=d_in[8];
  const void* bhh=d_in[9];
  const void* Wv =d_in[10];
  const void* bv =d_in[11];
  const void* Wl =d_in[12];
  const void* bl =d_in[13];

  char* w=(char*)d_ws;
  auto alloc=[&](size_t n){ char* p=w; w+=((n+255)&~(size_t)255); return p; };
  int*   flag =(int*)alloc(4);
  int*   cnt  =(int*)alloc(512*4);
  float* biasg=(float*)alloc((size_t)G_*4);
  float* b1f  =(float*)alloc((size_t)H_*4);
  float* blf  =(float*)alloc(32*4);
  float* cst  =(float*)alloc((size_t)B_*H_*4);
  u16*   hh   =(u16*)alloc((size_t)B_*SP1*H_*2);   // 67.6 MB
  u16*   xc   =(u16*)alloc((size_t)CR_*H_*2);      // 16.8 MB
  u16*   xg   =(u16*)alloc((size_t)CR_*G_*2);      // 67 MB fp16 xg chunk (CH_=32)
  // tiers
  size_t nW=((size_t)H_*F_ + 2*(size_t)G_*H_ + 32*(size_t)H_)*2 + 1024;
  bool pathW = ((size_t)(w-(char*)d_ws) + nW) <= ws_size;
  u16 *W1h=0,*Wihp=0,*Whhp=0,*WH=0;
  if(pathW){ W1h=(u16*)alloc((size_t)H_*F_*2); Wihp=(u16*)alloc((size_t)G_*H_*2);
             Whhp=(u16*)alloc((size_t)G_*H_*2); WH=(u16*)alloc((size_t)32*H_*2); }
  size_t nXC=(size_t)M_*H_*2 + 256;
  bool pathXC = pathW && (((size_t)(w-(char*)d_ws) + nXC) <= ws_size);
  u16* xcf=0; if(pathXC) xcf=(u16*)alloc((size_t)M_*H_*2);
  size_t nO=(size_t)M_*F_*2 + 256;
  bool pathO = pathXC && (((size_t)(w-(char*)d_ws) + nO) <= ws_size);
  u16* obsh=0; if(pathO) obsh=(u16*)alloc((size_t)M_*F_*2);

  detect<<<1,256,0,stream>>>((const u16*)obs, flag);
  {
    int total=G_+H_+19+512+B_*H_+B_*H_;
    prep<<<(total+255)/256,256,0,stream>>>(bih,bhh,b1,bl,bv,cx,hx, biasg,b1f,blf,cst,hh,cnt, flag);
  }
  if(pathW){
    size_t n=((size_t)H_*F_+2*(size_t)G_*H_+32*(size_t)H_)/8;
    convw<<<(int)((n+255)/256),256,0,stream>>>(W1,Wih,Whh,Wl,Wv, W1h,Wihp,Whhp,WH, flag);
  }
  if(pathO){
    size_t n=(size_t)M_*F_/8;
    convobs<<<(int)((n+255)/256),256,0,stream>>>(obs, obsh, flag);
  }
  if(pathXC){
    gemm128<0,0,0><<<dim3(H_/128, M_/128),256,0,stream>>>(
        pathO?(const void*)obsh:obs, pathW?(const void*)W1h:W1, xcf, b1f, flag,
        F_, F_, F_, H_, 0, pathO?2:-1, pathW?2:-1);
  }

  const int NC=S_/CH_;
  for(int c=0;c<NC;c++){
    int t0=c*CH_;
    if(!pathXC){
      gemm128<2,0,0><<<dim3(H_/128, CR_/128),256,0,stream>>>(
          obs, pathW?(const void*)W1h:W1, xc, b1f, flag, F_, F_, F_, H_, t0, -1, pathW?2:-1);
    }
    if(pathXC)
      gemm128<2,0,2><<<dim3(G_/128, CR_/128),256,0,stream>>>(
          xcf, Wihp, xg, biasg, flag, H_, H_, H_, G_, t0, 2, 2);
    else if(pathW)
      gemm128<0,0,2><<<dim3(G_/128, CR_/128),256,0,stream>>>(
          xc, Wihp, xg, biasg, flag, H_, H_, H_, G_, 0, 2, 2);
    else
      gemm128<0,1,2><<<dim3(G_/128, CR_/128),256,0,stream>>>(
          xc, Wih, xg, biasg, flag, H_, H_, H_, G_, 0, 2, -1);

    if(pathW)
      lstm_persist<<<256,512,0,stream>>>(hh, Whhp, xg, cst, cnt, t0);
    else
      for(int dt=0;dt<CH_;dt++)
        lstm_step<<<dim3(G_/64, B_/64),256,0,stream>>>(hh, t0+dt, dt, Whh, xg, cst, flag);
  }

  if(pathW)
    heads_gemm<<<dim3(M_/128),512,0,stream>>>(hh, WH, blf, acts, d_out, flag);
  else
    heads_full<<<dim3(M_/4),256,0,stream>>>(hh, Wl, Wv, blf, acts, d_out, flag);
}